// Round 27
// baseline (253.903 us; speedup 1.0000x reference)
//
#include <hip/hip_runtime.h>
#include <stdint.h>

typedef _Float16 f16;
typedef _Float16 half8 __attribute__((ext_vector_type(8)));
typedef __fp16 fp16x2 __attribute__((ext_vector_type(2)));
typedef float f32x4 __attribute__((ext_vector_type(4)));

#define NBATCH 16
#define NTOK 3136
#define NTOT 50176          // NBATCH*NTOK
#define NH 8
#define NA 49
#define NAP 64
#define TTOP 1568
#define SCALE 0.17677669529663687f
#define FPARTS 4

__device__ __forceinline__ f32x4 mfma16(half8 a, half8 b, f32x4 c) {
  return __builtin_amdgcn_mfma_f32_16x16x32_f16(a, b, c, 0, 0, 0);
}

__device__ __forceinline__ void gload16(const void* g, void* l) {
  __builtin_amdgcn_global_load_lds(
      (const __attribute__((address_space(1))) void*)g,
      (__attribute__((address_space(3))) void*)l, 16, 0, 0);
}

__device__ __forceinline__ half8 cvt8(float4 a, float4 b) {
  union { half8 hv; fp16x2 h2[4]; } u;
  u.h2[0] = __builtin_amdgcn_cvt_pkrtz(a.x, a.y);
  u.h2[1] = __builtin_amdgcn_cvt_pkrtz(a.z, a.w);
  u.h2[2] = __builtin_amdgcn_cvt_pkrtz(b.x, b.y);
  u.h2[3] = __builtin_amdgcn_cvt_pkrtz(b.z, b.w);
  return u.hv;
}

// ---------------- weight conversion ----------------
__global__ __launch_bounds__(256) void k_prep_w(const float* Wq, const float* Wkv, const float* Wproj,
                                                f16* wqkv, f16* wproj) {
  int total1 = 768 * 256;
  int total = total1 + 256 * 256;
  for (int i = blockIdx.x * 256 + threadIdx.x; i < total; i += gridDim.x * 256) {
    if (i < total1) {
      int j = i >> 8, k = i & 255;
      float v = (j < 256) ? Wq[j * 256 + k] : Wkv[(j - 256) * 256 + k];
      wqkv[i] = (f16)v;
    } else {
      int i2 = i - total1;
      wproj[i2] = (f16)Wproj[i2];
    }
  }
}

// ---------------- bias precompute ----------------
__global__ __launch_bounds__(256) void k_bias(const float* an_b, const float* na_b,
                                              const float* ah_b, const float* aw_b,
                                              const float* ha_b, const float* wa_b,
                                              float* pos_bias, f16* agbH) {
  int n = blockIdx.x * 256 + threadIdx.x;
  int h = blockIdx.y;
  if (n >= NTOK) return;
  int y = n / 56, x = n - y * 56;
  float py = (y + 0.5f) * 0.125f - 0.5f;
  float px = (x + 0.5f) * 0.125f - 0.5f;
  int iy0 = (int)floorf(py); float fy = py - (float)iy0;
  int ix0 = (int)floorf(px); float fx = px - (float)ix0;
  int y0 = max(iy0, 0), y1 = min(iy0 + 1, 6);
  int x0 = max(ix0, 0), x1 = min(ix0 + 1, 6);
  float w00 = (1.f - fy) * (1.f - fx), w01 = (1.f - fy) * fx;
  float w10 = fy * (1.f - fx), w11 = fy * fx;
  f16* abp = agbH + ((size_t)(h * NTOK + n)) * NAP;
  for (int a = 0; a < NA; ++a) {
    const float* pa = an_b + (h * NA + a) * 49;
    float up_an = w00 * pa[y0 * 7 + x0] + w01 * pa[y0 * 7 + x1] +
                  w10 * pa[y1 * 7 + x0] + w11 * pa[y1 * 7 + x1];
    const float* pn = na_b + (h * NA + a) * 49;
    float up_na = w00 * pn[y0 * 7 + x0] + w01 * pn[y0 * 7 + x1] +
                  w10 * pn[y1 * 7 + x0] + w11 * pn[y1 * 7 + x1];
    float pb = up_an + ah_b[(h * NA + a) * 56 + y] + aw_b[(h * NA + a) * 56 + x];
    pos_bias[((size_t)(h * NAP + a)) * NTOK + n] = pb;
    float ab = up_na + ha_b[(h * 56 + y) * NA + a] + wa_b[(h * 56 + x) * NA + a];
    abp[a] = (f16)ab;
  }
  for (int a = NA; a < NAP; ++a) {
    pos_bias[((size_t)(h * NAP + a)) * NTOK + n] = 0.f;
    abp[a] = (f16)0.f;
  }
}

// ---------------- qkv GEMM: BK=64, A f32 loaded DIRECT to MFMA fragments (no LDS round-trip) ----------------
// LDS: B only, 2 half-K subtiles of 8KB = 16KB. One latency exposure per iteration (single barrier
// waits for both A flat loads and B DMA). 32 MFMA per barrier pair.
__global__ __launch_bounds__(256) void k_gemm_qkv(const float* __restrict__ Af32,
                                                  const f16* __restrict__ Bw,
                                                  f16* __restrict__ CH) {
  __shared__ __align__(16) char lds[16384];
  const int N = 768;
  int per = gridDim.x >> 3;
  int wrk = (blockIdx.x & 7) * per + (blockIdx.x >> 3);
  int nNT = N >> 7;
  int mt = wrk / nNT, nt = wrk - mt * nNT;
  int m0 = mt * 128, n0 = nt * 128;
  int tid = threadIdx.x, w = tid >> 6, l = tid & 63, lr = l & 15, lg = l >> 4;
  int wm = w >> 1, wn = w & 1;
  f32x4 acc[4][4] = {};
  const char* Bb = (const char*)Bw + (size_t)n0 * 512;
  int rowB0 = 32 * w + (l >> 2);
  int rowB1 = rowB0 + 16;
  int koffB = (l & 3) * 16;
  char* ldsB0a = lds + (2 * w) * 1024;
  char* ldsB0b = lds + (2 * w + 1) * 1024;
  char* ldsB1a = lds + 8192 + (2 * w) * 1024;
  char* ldsB1b = lds + 8192 + (2 * w + 1) * 1024;
  // A fragment base: row m0 + wm*64 + m4*16 + lr, k-offset lg*8
  const float* Abase = Af32 + (size_t)(m0 + wm * 64 + lr) * 256 + lg * 8;

  for (int k0 = 0; k0 < 256; k0 += 64) {
    // B DMA (4 x 1KB per wave)
    gload16(Bb + (size_t)rowB0 * 512 + k0 * 2 + koffB, ldsB0a);
    gload16(Bb + (size_t)rowB1 * 512 + k0 * 2 + koffB, ldsB0b);
    gload16(Bb + (size_t)rowB0 * 512 + k0 * 2 + 64 + koffB, ldsB1a);
    gload16(Bb + (size_t)rowB1 * 512 + k0 * 2 + 64 + koffB, ldsB1b);
    // A fragment loads: 4 m4 x 2 K-halves x 2 float4 (per-row 128B contiguous)
    float4 av0a[4], av0b[4], av1a[4], av1b[4];
#pragma unroll
    for (int m4 = 0; m4 < 4; ++m4) {
      const float* ap = Abase + (size_t)m4 * 16 * 256 + k0;
      av0a[m4] = *(const float4*)ap;
      av0b[m4] = *(const float4*)(ap + 4);
      av1a[m4] = *(const float4*)(ap + 32);
      av1b[m4] = *(const float4*)(ap + 36);
    }
    // in-register f32 -> f16 fragments
    half8 af0[4], af1[4];
#pragma unroll
    for (int m4 = 0; m4 < 4; ++m4) {
      af0[m4] = cvt8(av0a[m4], av0b[m4]);
      af1[m4] = cvt8(av1a[m4], av1b[m4]);
    }
    __syncthreads();   // waits B DMA (and A loads, already consumed)
    half8 bf[4];
#pragma unroll
    for (int n4 = 0; n4 < 4; ++n4) {
      int row = wn * 64 + n4 * 16 + lr;
      bf[n4] = *(const half8*)(lds + row * 64 + lg * 16);
    }
#pragma unroll
    for (int m4 = 0; m4 < 4; ++m4)
#pragma unroll
      for (int n4 = 0; n4 < 4; ++n4)
        acc[m4][n4] = mfma16(af0[m4], bf[n4], acc[m4][n4]);
#pragma unroll
    for (int n4 = 0; n4 < 4; ++n4) {
      int row = wn * 64 + n4 * 16 + lr;
      bf[n4] = *(const half8*)(lds + 8192 + row * 64 + lg * 16);
    }
#pragma unroll
    for (int m4 = 0; m4 < 4; ++m4)
#pragma unroll
      for (int n4 = 0; n4 < 4; ++n4)
        acc[m4][n4] = mfma16(af1[m4], bf[n4], acc[m4][n4]);
    __syncthreads();
  }

  // C epilogue: route through LDS halves (16KB) for coalesced half8 stores to h-planes
  f16* cl = (f16*)lds;
  int rr = tid >> 2, c4 = tid & 3;
#pragma unroll
  for (int hm = 0; hm < 2; ++hm) {
    __syncthreads();
    if (wm == hm) {
#pragma unroll
      for (int m4 = 0; m4 < 4; ++m4)
#pragma unroll
        for (int n4 = 0; n4 < 4; ++n4)
#pragma unroll
          for (int r = 0; r < 4; ++r)
            cl[(m4 * 16 + lg * 4 + r) * 128 + wn * 64 + n4 * 16 + lr] = (f16)acc[m4][n4][r];
    }
    __syncthreads();
#pragma unroll
    for (int cc = 0; cc < 4; ++cc) {
      int pn = (n0 >> 5) + cc;
      half8 v = *(const half8*)(cl + rr * 128 + cc * 32 + c4 * 8);
      *(half8*)(CH + ((size_t)pn * NTOT + m0 + hm * 64 + rr) * 32 + c4 * 8) = v;
    }
  }
}

// ---------------- proj GEMM (m97 structure, BK=32, gload_lds A planes) ----------------
__global__ __launch_bounds__(256) void k_gemm_proj(const f16* __restrict__ A, const f16* __restrict__ Bw,
                                                   float* __restrict__ Cf32,
                                                   const float* __restrict__ bias, int N) {
  __shared__ __align__(16) char lds[16384];
  int per = gridDim.x >> 3;
  int wrk = (blockIdx.x & 7) * per + (blockIdx.x >> 3);
  int nNT = N >> 7;
  int mt = wrk / nNT, nt = wrk - mt * nNT;
  int m0 = mt * 128, n0 = nt * 128;
  int tid = threadIdx.x, w = tid >> 6, l = tid & 63, lr = l & 15, lg = l >> 4;
  int wm = w >> 1, wn = w & 1;
  f32x4 acc[4][4] = {};
  const char* Bb = (const char*)Bw + (size_t)n0 * 512;
  int rowA0 = 32 * w + (l >> 2);
  int rowA1 = rowA0 + 16;
  int koff = (l & 3) * 16;
  char* ldsA0 = lds + (2 * w) * 1024;
  char* ldsA1 = lds + (2 * w + 1) * 1024;
  char* ldsB0 = lds + 8192 + (2 * w) * 1024;
  char* ldsB1 = lds + 8192 + (2 * w + 1) * 1024;

  for (int k0 = 0; k0 < 256; k0 += 32) {
    const char* Ab = (const char*)A + ((size_t)(k0 >> 5) * NTOT + m0) * 64;
    gload16(Ab + (size_t)rowA0 * 64 + koff, ldsA0);
    gload16(Ab + (size_t)rowA1 * 64 + koff, ldsA1);
    gload16(Bb + (size_t)rowA0 * 512 + k0 * 2 + koff, ldsB0);
    gload16(Bb + (size_t)rowA1 * 512 + k0 * 2 + koff, ldsB1);
    __syncthreads();
    half8 af[4], bf[4];
#pragma unroll
    for (int m4 = 0; m4 < 4; ++m4) {
      int row = wm * 64 + m4 * 16 + lr;
      af[m4] = *(const half8*)(lds + row * 64 + lg * 16);
    }
#pragma unroll
    for (int n4 = 0; n4 < 4; ++n4) {
      int row = wn * 64 + n4 * 16 + lr;
      bf[n4] = *(const half8*)(lds + 8192 + row * 64 + lg * 16);
    }
#pragma unroll
    for (int m4 = 0; m4 < 4; ++m4)
#pragma unroll
      for (int n4 = 0; n4 < 4; ++n4)
        acc[m4][n4] = mfma16(af[m4], bf[n4], acc[m4][n4]);
    __syncthreads();
  }

#pragma unroll
  for (int n4 = 0; n4 < 4; ++n4) {
    int n = n0 + wn * 64 + n4 * 16 + lr;
#pragma unroll
    for (int m4 = 0; m4 < 4; ++m4)
#pragma unroll
      for (int r = 0; r < 4; ++r) {
        int m = m0 + wm * 64 + m4 * 16 + lg * 4 + r;
        Cf32[(size_t)m * N + n] = acc[m4][n4][r] + bias[n];
      }
  }
}

// ---------------- agent pooling (scaled) + token means ----------------
__global__ __launch_bounds__(256) void k_pool_tw(const f16* qkvH, f16* agent, float* tw) {
  int bh = blockIdx.x, b = bh >> 3, h = bh & 7;
  int tid = threadIdx.x;
  const f16* qp0 = qkvH + ((size_t)h * NTOT + (size_t)b * NTOK) * 32;
  {
    int a = tid >> 2, c = tid & 3;
    float s8[8] = {};
    if (a < NA) {
      int dh = a / 7, dwi = a - dh * 7;
      for (int i = 0; i < 8; ++i)
#pragma unroll
        for (int j = 0; j < 8; ++j) {
          int tok = (dh * 8 + i) * 56 + dwi * 8 + j;
          half8 v = *(const half8*)(qp0 + (size_t)tok * 32 + c * 8);
#pragma unroll
          for (int e = 0; e < 8; ++e) s8[e] += (float)v[e];
        }
    }
    half8 o;
#pragma unroll
    for (int e = 0; e < 8; ++e) o[e] = (f16)(s8[e] * (SCALE / 64.f));
    *(half8*)(agent + (size_t)bh * NAP * 32 + a * 32 + c * 8) = o;
  }
  for (int n = tid; n < NTOK; n += 256) {
    const half8* qp = (const half8*)(qp0 + (size_t)n * 32);
    float sum = 0.f;
#pragma unroll
    for (int j = 0; j < 4; ++j) {
      half8 v = qp[j];
#pragma unroll
      for (int e = 0; e < 8; ++e) sum += (float)v[e];
    }
    tw[(size_t)bh * NTOK + n] = sum * (1.f / 32.f);
  }
}

// ---------------- two-phase exact top-k (desc value, asc index) ----------------
template <int NE, int J>
__device__ __forceinline__ void stage_local(unsigned long long (&key)[NE], int kmask, int base) {
#pragma unroll
  for (int e = 0; e < NE; ++e) {
    if ((e & J) == 0) {
      bool desc = (((base + e) & kmask) == 0);
      unsigned long long a = key[e], c = key[e | J];
      if ((a < c) == desc) { key[e] = c; key[e | J] = a; }
    }
  }
}

__global__ __launch_bounds__(256, 1) void k_sort1(const float* tw, unsigned long long* keys64) {
  __shared__ unsigned long long lk[2048 + 128];
  int bh = blockIdx.x >> 1, half = blockIdx.x & 1;
  int tid = threadIdx.x;
  const float* p = tw + (size_t)bh * NTOK;
  int gbase = half * 2048 + tid * 8;
  unsigned long long key[8];
#pragma unroll
  for (int e = 0; e < 8; ++e) {
    int s = gbase + e;
    float v = (s < NTOK) ? p[s] : -1e30f;
    unsigned ub = __float_as_uint(v);
    ub = (ub & 0x80000000u) ? ~ub : (ub | 0x80000000u);
    unsigned low = (s < NTOK) ? ~(unsigned)s : 0u;
    key[e] = ((unsigned long long)ub << 32) | low;
  }
  stage_local<8, 1>(key, 2, gbase);
  stage_local<8, 2>(key, 4, gbase); stage_local<8, 1>(key, 4, gbase);
  stage_local<8, 4>(key, 8, gbase); stage_local<8, 2>(key, 8, gbase); stage_local<8, 1>(key, 8, gbase);
  for (int k = 16; k <= 2048; k <<= 1) {
    bool desc = ((gbase & k) == 0);
    for (int j = k >> 1; j >= 8; j >>= 1) {
      int m = j >> 3;
      bool takeMax = (((tid & m) == 0) == desc);
      unsigned long long pv[8];
      if (m <= 32) {
#pragma unroll
        for (int e = 0; e < 8; ++e) pv[e] = __shfl_xor(key[e], m, 64);
      } else {
        __syncthreads();
#pragma unroll
        for (int e = 0; e < 8; ++e) { int ix = tid * 8 + e; lk[ix + (ix >> 4)] = key[e]; }
        __syncthreads();
        int pb = (tid ^ m) * 8;
#pragma unroll
        for (int e = 0; e < 8; ++e) { int ix = pb + e; pv[e] = lk[ix + (ix >> 4)]; }
      }
#pragma unroll
      for (int e = 0; e < 8; ++e)
        key[e] = takeMax ? (key[e] > pv[e] ? key[e] : pv[e])
                         : (key[e] < pv[e] ? key[e] : pv[e]);
    }
    stage_local<8, 4>(key, k, gbase);
    stage_local<8, 2>(key, k, gbase);
    stage_local<8, 1>(key, k, gbase);
  }
  unsigned long long* op = keys64 + (size_t)bh * 4096 + gbase;
#pragma unroll
  for (int e = 0; e < 8; ++e) op[e] = key[e];
}

__global__ __launch_bounds__(256, 1) void k_sort2(const unsigned long long* keys64, int* topidx) {
  __shared__ unsigned long long lk[4096 + 256];
  int bh = blockIdx.x, tid = threadIdx.x;
  const unsigned long long* ip = keys64 + (size_t)bh * 4096 + (size_t)tid * 16;
  unsigned long long key[16];
#pragma unroll
  for (int e = 0; e < 16; ++e) key[e] = ip[e];
  int base = tid * 16;
  for (int j = 2048; j >= 16; j >>= 1) {
    int m = j >> 4;
    bool takeMax = ((tid & m) == 0);
    unsigned long long pv[16];
    if (m <= 32) {
#pragma unroll
      for (int e = 0; e < 16; ++e) pv[e] = __shfl_xor(key[e], m, 64);
    } else {
      __syncthreads();
#pragma unroll
      for (int e = 0; e < 16; ++e) { int ix = base + e; lk[ix + (ix >> 4)] = key[e]; }
      __syncthreads();
      int pb = (tid ^ m) * 16;
#pragma unroll
      for (int e = 0; e < 16; ++e) { int ix = pb + e; pv[e] = lk[ix + (ix >> 4)]; }
    }
#pragma unroll
    for (int e = 0; e < 16; ++e)
      key[e] = takeMax ? (key[e] > pv[e] ? key[e] : pv[e])
                       : (key[e] < pv[e] ? key[e] : pv[e]);
  }
  stage_local<16, 8>(key, 4096, base);
  stage_local<16, 4>(key, 4096, base);
  stage_local<16, 2>(key, 4096, base);
  stage_local<16, 1>(key, 4096, base);
  if (tid < TTOP / 16) {
    int* op = topidx + (size_t)bh * TTOP + base;
#pragma unroll
    for (int e = 0; e < 16; ++e) op[e] = (int)(~(unsigned)key[e]);
  }
}

// ---------------- v transpose: vt[bh][d=32][n=3136] ----------------
__global__ __launch_bounds__(256) void k_vt(const f16* qkvH, f16* vt) {
  __shared__ __align__(16) f16 t[64][40];
  int bh = blockIdx.y, b = bh >> 3, h = bh & 7;
  int n0 = blockIdx.x * 64;
  int tid = threadIdx.x;
  const f16* vp = qkvH + ((size_t)(16 + h) * NTOT + (size_t)b * NTOK + n0) * 32;
  {
    int nl = tid >> 2, c = tid & 3;
    *(half8*)(&t[nl][c * 8]) = *(const half8*)(vp + (size_t)nl * 32 + c * 8);
  }
  __syncthreads();
  for (int s = tid; s < 64 * 32; s += 256) {
    int d = s >> 6, nl = s & 63;
    vt[((size_t)(bh * 32 + d)) * NTOK + n0 + nl] = t[nl][d];
  }
}

// ---------------- fused agent attention, split-n partials ----------------
__global__ __launch_bounds__(256) void k_flash(const f16* qkvH, const f16* agent, const f16* vt,
                                               const float* pos_bias, float* opart, float* rspart) {
  __shared__ __align__(16) f16 pbuf[4][64][40];
  __shared__ float ored[64][33];
  __shared__ float rssum[64];
  int part = blockIdx.x, bh = blockIdx.y, b = bh >> 3, h = bh & 7;
  int tid = threadIdx.x, w = tid >> 6, l = tid & 63, lr = l & 15, lg = l >> 4;
  half8 afrag[4];
#pragma unroll
  for (int mt = 0; mt < 4; ++mt)
    afrag[mt] = *(const half8*)(agent + ((size_t)bh * 64 + mt * 16 + lr) * 32 + lg * 8);
  f32x4 o[4][2] = {};
  float rs[4][4] = {};
  const f16* kbase = qkvH + ((size_t)(8 + h) * NTOT + (size_t)b * NTOK) * 32;
  const f16* vtb = vt + (size_t)bh * 32 * NTOK;
  const float* pbb = pos_bias + (size_t)h * NAP * NTOK;
  f32x4 zero = {};
  for (int n0 = (part * 4 + w) * 32; n0 < NTOK; n0 += 512) {
#pragma unroll
    for (int t2 = 0; t2 < 2; ++t2) {
      int nc = n0 + t2 * 16;
      half8 kf = *(const half8*)(kbase + (size_t)(nc + lr) * 32 + lg * 8);
#pragma unroll
      for (int mt = 0; mt < 4; ++mt) {
        f32x4 s = mfma16(afrag[mt], kf, zero);
#pragma unroll
        for (int r = 0; r < 4; ++r) {
          int a = mt * 16 + lg * 4 + r;
          float pv = __expf(s[r] + pbb[(size_t)a * NTOK + nc + lr]);
          rs[mt][r] += pv;
          pbuf[w][a][t2 * 16 + lr] = (f16)pv;
        }
      }
    }
    half8 pf[4];
#pragma unroll
    for (int mt = 0; mt < 4; ++mt)
      pf[mt] = *(const half8*)(&pbuf[w][mt * 16 + lr][lg * 8]);
#pragma unroll
    for (int dt = 0; dt < 2; ++dt) {
      half8 vf = *(const half8*)(vtb + (size_t)(dt * 16 + lr) * NTOK + n0 + lg * 8);
#pragma unroll
      for (int mt = 0; mt < 4; ++mt)
        o[mt][dt] = mfma16(pf[mt], vf, o[mt][dt]);
    }
  }
#pragma unroll
  for (int mt = 0; mt < 4; ++mt)
#pragma unroll
    for (int r = 0; r < 4; ++r) {
      float v = rs[mt][r];
      for (int off = 1; off < 16; off <<= 1) v += __shfl_xor(v, off, 64);
      rs[mt][r] = v;
    }
  for (int s = tid; s < 64 * 33; s += 256) ((float*)ored)[s] = 0.f;
  if (tid < 64) rssum[tid] = 0.f;
  __syncthreads();
  for (int ww = 0; ww < 4; ++ww) {
    if (w == ww) {
      if (lr == 0)
#pragma unroll
        for (int mt = 0; mt < 4; ++mt)
#pragma unroll
          for (int r = 0; r < 4; ++r) rssum[mt * 16 + lg * 4 + r] += rs[mt][r];
#pragma unroll
      for (int mt = 0; mt < 4; ++mt)
#pragma unroll
        for (int dt = 0; dt < 2; ++dt)
#pragma unroll
          for (int r = 0; r < 4; ++r)
            ored[mt * 16 + lg * 4 + r][dt * 16 + lr] += o[mt][dt][r];
    }
    __syncthreads();
  }
  int pp = bh * FPARTS + part;
  for (int s = tid; s < NA * 32; s += 256) {
    int a = s >> 5, d = s & 31;
    opart[((size_t)pp * 64 + a) * 32 + d] = ored[a][d];
  }
  if (tid < NA) rspart[(size_t)pp * 64 + tid] = rssum[tid];
}

// ---------------- k_fred: reduce flash partials -> agent_v ----------------
__global__ __launch_bounds__(256) void k_fred(const float* opart, const float* rspart, float* agv) {
  int bh = blockIdx.x, tid = threadIdx.x;
  for (int s = tid; s < NA * 32; s += 256) {
    int a = s >> 5, d = s & 31;
    float o = 0.f, rs = 0.f;
#pragma unroll
    for (int p = 0; p < FPARTS; ++p) {
      int pp = bh * FPARTS + p;
      o += opart[((size_t)pp * 64 + a) * 32 + d];
      rs += rspart[(size_t)pp * 64 + a];
    }
    agv[(size_t)bh * NA * 32 + s] = o / rs;
  }
}

// ---------------- k_po: fused q2-gather -> resize -> softmax -> P@avT + dwconv -> preH ----------------
__global__ __launch_bounds__(256) void k_po(const f16* __restrict__ qkvH, const f16* __restrict__ agent,
                                            const int* __restrict__ topidx,
                                            const f16* __restrict__ agbH,
                                            const float* __restrict__ agent_v,
                                            const float* __restrict__ dwc_w,
                                            const float* __restrict__ dwc_b,
                                            f16* __restrict__ preH) {
  __shared__ __align__(16) char uq[9728];         // q2buf[64][76] f16, later ctile[112][40] f16
  __shared__ __align__(16) f16 pbuf[7 * 8 * 16 * 8];
  __shared__ __align__(16) f16 avT[32][72];
  __shared__ __align__(16) f16 wconvh[9][32];
  __shared__ float bconv[32];
  f16 (*q2buf)[76] = (f16(*)[76])uq;
  f16 (*ctile)[40] = (f16(*)[40])uq;
  int wrk = (blockIdx.x & 7) * 448 + (blockIdx.x >> 3);
  int h = wrk / 448;
  int rem = wrk - h * 448;
  int b = rem / 28;
  int chunk = rem - b * 28;
  int bh = b * 8 + h;
  int tid = threadIdx.x, w = tid >> 6, l = tid & 63, lr = l & 15, lg = l >> 4;
  const f16* qplane = qkvH + ((size_t)h * NTOT + (size_t)b * NTOK) * 32;
  const f16* vp = qkvH + ((size_t)(16 + h) * NTOT + (size_t)b * NTOK) * 32;
  for (int s = tid; s < 32 * 64; s += 256) {
    int d = s >> 6, a = s & 63;
    avT[d][a] = (a < NA) ? (f16)agent_v[((size_t)bh * NA + a) * 32 + d] : (f16)0.f;
  }
  for (int s = tid; s < 32 * 9; s += 256) {
    int d = s / 9, t = s - d * 9;
    wconvh[t][d] = (f16)dwc_w[(size_t)(h * 32 + d) * 9 + t];
  }
  if (tid < 32) bconv[tid] = dwc_b[h * 32 + tid];
  half8 bfrag[4];
#pragma unroll
  for (int nt = 0; nt < 4; ++nt)
    bfrag[nt] = *(const half8*)(agent + ((size_t)bh * 64 + nt * 16 + lr) * 32 + lg * 8);
  int jbase = chunk * 56 - 4;
  f32x4 zero = {};
  {
    int j = jbase + w * 16 + lr;
    int jc = min(max(j, 0), TTOP - 1);
    int tok = topidx[(size_t)bh * TTOP + jc];
    half8 qf = *(const half8*)(qplane + (size_t)tok * 32 + lg * 8);
#pragma unroll
    for (int nt = 0; nt < 4; ++nt) {
      f32x4 s = mfma16(qf, bfrag[nt], zero);
#pragma unroll
      for (int r = 0; r < 4; ++r)
        q2buf[w * 16 + lg * 4 + r][nt * 16 + lr] = (f16)s[r];
    }
  }
  __syncthreads();
  if (tid < 224) {
    int ltok = tid >> 1, hc = tid & 1;
    int g = chunk * 112 + ltok;
    int hi = g >> 1;
    int jA, jB; float wAq, wBq;
    if (g & 1) { jA = hi; jB = hi + 1; wAq = 0.75f; wBq = 0.25f; }
    else       { jA = hi - 1; jB = hi; wAq = 0.25f; wBq = 0.75f; }
    jA = min(max(jA, 0), TTOP - 1);
    jB = min(max(jB, 0), TTOP - 1);
    int lA = jA - jbase, lB = jB - jbase;
    const f16* ab = agbH + ((size_t)(h * NTOK + g)) * NAP + hc * 32;
    half8 bias8[4];
#pragma unroll
    for (int cc = 0; cc < 4; ++cc) bias8[cc] = *(const half8*)(ab + cc * 8);
    f16 wAh = (f16)wAq, wBh = (f16)wBq;
    half8 wA8 = {wAh, wAh, wAh, wAh, wAh, wAh, wAh, wAh};
    half8 wB8 = {wBh, wBh, wBh, wBh, wBh, wBh, wBh, wBh};
    float ssum = 0.f;
    half8 oo[4];
#pragma unroll
    for (int cc = 0; cc < 4; ++cc) {
      int c = hc * 4 + cc;
      half8 a8 = *(const half8*)(&q2buf[lA][c * 8]);
      half8 b8 = *(const half8*)(&q2buf[lB][c * 8]);
      half8 v8 = a8 * wA8 + b8 * wB8 + bias8[cc];
#pragma unroll
      for (int e = 0; e < 8; ++e) {
        int a = c * 8 + e;
        float pv = 0.f;
        if (a < NA) {
          pv = __expf((float)v8[e]);
          ssum += pv;
        }
        oo[cc][e] = (f16)pv;
      }
    }
    ssum += __shfl_xor(ssum, 1, 64);
    f16 invs = (f16)(1.f / ssum);
    half8 iv8 = {invs, invs, invs, invs, invs, invs, invs, invs};
    int lt = ltok >> 4, lrr = ltok & 15;
#pragma unroll
    for (int cc = 0; cc < 4; ++cc) {
      int c = hc * 4 + cc;
      *(half8*)(pbuf + ((size_t)(lt * 8 + c) * 16 + lrr) * 8) = oo[cc] * iv8;
    }
  }
  __syncthreads();
  half8 bf[2][2];
#pragma unroll
  for (int nt = 0; nt < 2; ++nt)
#pragma unroll
    for (int ks = 0; ks < 2; ++ks)
      bf[nt][ks] = *(const half8*)(&avT[0][0] + (size_t)(nt * 16 + lr) * 72 + ks * 32 + lg * 8);
#pragma unroll
  for (int i = 0; i < 2; ++i) {
    int lt = w * 2 + i;
    if (lt >= 7) continue;
    half8 pa0 = *(const half8*)(pbuf + ((size_t)(lt * 8 + lg) * 16 + lr) * 8);
    half8 pa1 = *(const half8*)(pbuf + ((size_t)(lt * 8 + 4 + lg) * 16 + lr) * 8);
    f32x4 acc0 = {}, acc1 = {};
    acc0 = mfma16(pa0, bf[0][0], acc0);
    acc0 = mfma16(pa1, bf[0][1], acc0);
    acc1 = mfma16(pa0, bf[1][0], acc1);
    acc1 = mfma16(pa1, bf[1][1], acc1);
    int ltrow = lt * 16 + lg * 4;
#pragma unroll
    for (int r = 0; r < 4; ++r) {
      ctile[ltrow + r][lr] = (f16)acc0[r];
      ctile[ltrow + r][16 + lr] = (f16)acc1[r];
    }
  }
  if (tid >= 224) return;
  int ltok = tid >> 1, hc = tid & 1;
  int g = chunk * 112 + ltok;
  int ly = ltok / 56, x = ltok - ly * 56;
  int y = chunk * 2 + ly;
  half8 acch[2] = {};
#pragma unroll
  for (int ky = 0; ky < 3; ++ky) {
    int gy = y + ky - 1;
    if (gy < 0 || gy >= 56) continue;
#pragma unroll
    for (int kx = 0; kx < 3; ++kx) {
      int xx = x + kx - 1;
      if (xx < 0 || xx >= 56) continue;
      int t = ky * 3 + kx;
      const f16* vt9 = vp + (size_t)(gy * 56 + xx) * 32 + hc * 16;
#pragma unroll
      for (int c = 0; c < 2; ++c) {
        half8 wv = *(const half8*)(&wconvh[t][hc * 16 + c * 8]);
        half8 vv = *(const half8*)(vt9 + c * 8);
        acch[c] += wv * vv;
      }
    }
  }
  f16* op = preH + ((size_t)h * NTOT + (size_t)b * NTOK + g) * 32 + hc * 16;
#pragma unroll
  for (int c = 0; c < 2; ++c) {
    half8 cv = *(const half8*)(&ctile[ltok][hc * 16 + c * 8]);
    half8 o;
#pragma unroll
    for (int e = 0; e < 8; ++e)
      o[e] = (f16)((float)cv[e] + bconv[hc * 16 + c * 8 + e] + (float)acch[c][e]);
    *(half8*)(op + c * 8) = o;
  }
}

extern "C" void kernel_launch(void* const* d_in, const int* in_sizes, int n_in,
                              void* d_out, int out_size, void* d_ws, size_t ws_size,
                              hipStream_t stream) {
  const float* x     = (const float*)d_in[0];
  const float* Wq    = (const float*)d_in[3];
  const float* Wkv   = (const float*)d_in[4];
  const float* Wproj = (const float*)d_in[5];
  const float* bproj = (const float*)d_in[6];
  const float* dwc_w = (const float*)d_in[7];
  const float* dwc_b = (const float*)d_in[8];
  const float* an_b  = (const float*)d_in[9];
  const float* na_b  = (const float*)d_in[10];
  const float* ah_b  = (const float*)d_in[11];
  const float* aw_b  = (const float*)d_in[12];
  const float* ha_b  = (const float*)d_in[13];
  const float* wa_b  = (const float*)d_in[14];

  char* ws = (char*)d_ws;
  size_t off = 0;
  auto alloc = [&](size_t bytes) {
    void* p = ws + off;
    off = (off + bytes + 255) & ~(size_t)255;
    return p;
  };
  f16* wqkv    = (f16*)alloc((size_t)768 * 256 * 2);
  f16* wproj   = (f16*)alloc((size_t)256 * 256 * 2);
  f16* qkvH    = (f16*)alloc((size_t)24 * NTOT * 32 * 2);
  float* posb  = (float*)alloc((size_t)8 * NAP * NTOK * 4);
  f16* agbH    = (f16*)alloc((size_t)8 * NTOK * NAP * 2);
  f16* agent   = (f16*)alloc((size_t)128 * NAP * 32 * 2);
  float* tw    = (float*)alloc((size_t)128 * NTOK * 4);
  int* topidx  = (int*)alloc((size_t)128 * TTOP * 4);
  unsigned long long* keys64 = (unsigned long long*)alloc((size_t)128 * 4096 * 8);
  f16* vt      = (f16*)alloc((size_t)128 * 32 * NTOK * 2);
  float* agv   = (float*)alloc((size_t)128 * NA * 32 * 4);
  float* opart = (float*)alloc((size_t)128 * FPARTS * 64 * 32 * 4);
  float* rspart= (float*)alloc((size_t)128 * FPARTS * 64 * 4);
  f16* preH    = (f16*)alloc((size_t)8 * NTOT * 32 * 2);

  k_prep_w<<<1024, 256, 0, stream>>>(Wq, Wkv, Wproj, wqkv, wproj);
  k_bias<<<dim3(13, 8), 256, 0, stream>>>(an_b, na_b, ah_b, aw_b, ha_b, wa_b, posb, agbH);
  k_gemm_qkv<<<2352, 256, 0, stream>>>(x, wqkv, qkvH);
  k_pool_tw<<<128, 256, 0, stream>>>(qkvH, agent, tw);
  k_sort1<<<256, 256, 0, stream>>>(tw, keys64);
  k_sort2<<<128, 256, 0, stream>>>(keys64, topidx);
  k_vt<<<dim3(49, 128), 256, 0, stream>>>(qkvH, vt);
  k_flash<<<dim3(FPARTS, 128), 256, 0, stream>>>(qkvH, agent, vt, posb, opart, rspart);
  k_fred<<<128, 256, 0, stream>>>(opart, rspart, agv);
  k_po<<<3584, 256, 0, stream>>>(qkvH, agent, topidx, agbH, agv, dwc_w, dwc_b, preH);
  k_gemm_proj<<<784, 256, 0, stream>>>(preH, wproj, (float*)d_out, bproj, 256);
}

// Round 28
// 207.441 us; speedup vs baseline: 1.2240x; 1.2240x over previous
//
#include <hip/hip_runtime.h>
#include <stdint.h>

typedef _Float16 f16;
typedef _Float16 half8 __attribute__((ext_vector_type(8)));
typedef __fp16 fp16x2 __attribute__((ext_vector_type(2)));
typedef float f32x4 __attribute__((ext_vector_type(4)));

#define NBATCH 16
#define NTOK 3136
#define NTOT 50176          // NBATCH*NTOK
#define NH 8
#define NA 49
#define NAP 64
#define TTOP 1568
#define SCALE 0.17677669529663687f
#define FPARTS 4

__device__ __forceinline__ f32x4 mfma16(half8 a, half8 b, f32x4 c) {
  return __builtin_amdgcn_mfma_f32_16x16x32_f16(a, b, c, 0, 0, 0);
}

__device__ __forceinline__ void gload16(const void* g, void* l) {
  __builtin_amdgcn_global_load_lds(
      (const __attribute__((address_space(1))) void*)g,
      (__attribute__((address_space(3))) void*)l, 16, 0, 0);
}

// ---------------- weight conversion ----------------
__global__ __launch_bounds__(256) void k_prep_w(const float* Wq, const float* Wkv, const float* Wproj,
                                                f16* wqkv, f16* wproj) {
  int total1 = 768 * 256;
  int total = total1 + 256 * 256;
  for (int i = blockIdx.x * 256 + threadIdx.x; i < total; i += gridDim.x * 256) {
    if (i < total1) {
      int j = i >> 8, k = i & 255;
      float v = (j < 256) ? Wq[j * 256 + k] : Wkv[(j - 256) * 256 + k];
      wqkv[i] = (f16)v;
    } else {
      int i2 = i - total1;
      wproj[i2] = (f16)Wproj[i2];
    }
  }
}

// ---------------- bias precompute ----------------
__global__ __launch_bounds__(256) void k_bias(const float* an_b, const float* na_b,
                                              const float* ah_b, const float* aw_b,
                                              const float* ha_b, const float* wa_b,
                                              float* pos_bias, f16* agbH) {
  int n = blockIdx.x * 256 + threadIdx.x;
  int h = blockIdx.y;
  if (n >= NTOK) return;
  int y = n / 56, x = n - y * 56;
  float py = (y + 0.5f) * 0.125f - 0.5f;
  float px = (x + 0.5f) * 0.125f - 0.5f;
  int iy0 = (int)floorf(py); float fy = py - (float)iy0;
  int ix0 = (int)floorf(px); float fx = px - (float)ix0;
  int y0 = max(iy0, 0), y1 = min(iy0 + 1, 6);
  int x0 = max(ix0, 0), x1 = min(ix0 + 1, 6);
  float w00 = (1.f - fy) * (1.f - fx), w01 = (1.f - fy) * fx;
  float w10 = fy * (1.f - fx), w11 = fy * fx;
  f16* abp = agbH + ((size_t)(h * NTOK + n)) * NAP;
  for (int a = 0; a < NA; ++a) {
    const float* pa = an_b + (h * NA + a) * 49;
    float up_an = w00 * pa[y0 * 7 + x0] + w01 * pa[y0 * 7 + x1] +
                  w10 * pa[y1 * 7 + x0] + w11 * pa[y1 * 7 + x1];
    const float* pn = na_b + (h * NA + a) * 49;
    float up_na = w00 * pn[y0 * 7 + x0] + w01 * pn[y0 * 7 + x1] +
                  w10 * pn[y1 * 7 + x0] + w11 * pn[y1 * 7 + x1];
    float pb = up_an + ah_b[(h * NA + a) * 56 + y] + aw_b[(h * NA + a) * 56 + x];
    pos_bias[((size_t)(h * NAP + a)) * NTOK + n] = pb;
    float ab = up_na + ha_b[(h * 56 + y) * NA + a] + wa_b[(h * 56 + x) * NA + a];
    abp[a] = (f16)ab;
  }
  for (int a = NA; a < NAP; ++a) {
    pos_bias[((size_t)(h * NAP + a)) * NTOK + n] = 0.f;
    abp[a] = (f16)0.f;
  }
}

// ---------------- qkv GEMM: BK=64, A f32 reg-staged through LDS, half-K subtiles (64B rows) ----------------
// LDS: A0 8KB | A1 8KB | B0 8KB | B1 8KB = 32KB. 4 K-iterations, 32 MFMA per barrier pair.
__global__ __launch_bounds__(256) void k_gemm_qkv(const float* __restrict__ Af32,
                                                  const f16* __restrict__ Bw,
                                                  f16* __restrict__ CH) {
  __shared__ __align__(16) char lds[32768];
  const int N = 768;
  int per = gridDim.x >> 3;
  int wrk = (blockIdx.x & 7) * per + (blockIdx.x >> 3);
  int nNT = N >> 7;
  int mt = wrk / nNT, nt = wrk - mt * nNT;
  int m0 = mt * 128, n0 = nt * 128;
  int tid = threadIdx.x, w = tid >> 6, l = tid & 63, lr = l & 15, lg = l >> 4;
  int wm = w >> 1, wn = w & 1;
  f32x4 acc[4][4] = {};
  const char* Bb = (const char*)Bw + (size_t)n0 * 512;
  int rs0 = tid >> 2, qs0 = tid & 3;
  int rs1 = rs0 + 64;
  int rowB0 = 32 * w + (l >> 2);
  int rowB1 = rowB0 + 16;
  int koffB = (l & 3) * 16;
  char* ldsB0a = lds + 16384 + (2 * w) * 1024;
  char* ldsB0b = lds + 16384 + (2 * w + 1) * 1024;
  char* ldsB1a = lds + 24576 + (2 * w) * 1024;
  char* ldsB1b = lds + 24576 + (2 * w + 1) * 1024;

  for (int k0 = 0; k0 < 256; k0 += 64) {
    const float* s00 = Af32 + (size_t)(m0 + rs0) * 256 + k0 + qs0 * 8;
    const float* s10 = Af32 + (size_t)(m0 + rs1) * 256 + k0 + qs0 * 8;
    const float* s01 = s00 + 32;
    const float* s11 = s10 + 32;
    float4 a00 = *(const float4*)s00, a00b = *(const float4*)(s00 + 4);
    float4 a10 = *(const float4*)s10, a10b = *(const float4*)(s10 + 4);
    float4 a01 = *(const float4*)s01, a01b = *(const float4*)(s01 + 4);
    float4 a11 = *(const float4*)s11, a11b = *(const float4*)(s11 + 4);
    gload16(Bb + (size_t)rowB0 * 512 + k0 * 2 + koffB, ldsB0a);
    gload16(Bb + (size_t)rowB1 * 512 + k0 * 2 + koffB, ldsB0b);
    gload16(Bb + (size_t)rowB0 * 512 + k0 * 2 + 64 + koffB, ldsB1a);
    gload16(Bb + (size_t)rowB1 * 512 + k0 * 2 + 64 + koffB, ldsB1b);
    {
      union { half8 hv; fp16x2 h2[4]; } u;
      u.h2[0] = __builtin_amdgcn_cvt_pkrtz(a00.x, a00.y);
      u.h2[1] = __builtin_amdgcn_cvt_pkrtz(a00.z, a00.w);
      u.h2[2] = __builtin_amdgcn_cvt_pkrtz(a00b.x, a00b.y);
      u.h2[3] = __builtin_amdgcn_cvt_pkrtz(a00b.z, a00b.w);
      *(half8*)(lds + rs0 * 64 + qs0 * 16) = u.hv;
      u.h2[0] = __builtin_amdgcn_cvt_pkrtz(a10.x, a10.y);
      u.h2[1] = __builtin_amdgcn_cvt_pkrtz(a10.z, a10.w);
      u.h2[2] = __builtin_amdgcn_cvt_pkrtz(a10b.x, a10b.y);
      u.h2[3] = __builtin_amdgcn_cvt_pkrtz(a10b.z, a10b.w);
      *(half8*)(lds + rs1 * 64 + qs0 * 16) = u.hv;
      u.h2[0] = __builtin_amdgcn_cvt_pkrtz(a01.x, a01.y);
      u.h2[1] = __builtin_amdgcn_cvt_pkrtz(a01.z, a01.w);
      u.h2[2] = __builtin_amdgcn_cvt_pkrtz(a01b.x, a01b.y);
      u.h2[3] = __builtin_amdgcn_cvt_pkrtz(a01b.z, a01b.w);
      *(half8*)(lds + 8192 + rs0 * 64 + qs0 * 16) = u.hv;
      u.h2[0] = __builtin_amdgcn_cvt_pkrtz(a11.x, a11.y);
      u.h2[1] = __builtin_amdgcn_cvt_pkrtz(a11.z, a11.w);
      u.h2[2] = __builtin_amdgcn_cvt_pkrtz(a11b.x, a11b.y);
      u.h2[3] = __builtin_amdgcn_cvt_pkrtz(a11b.z, a11b.w);
      *(half8*)(lds + 8192 + rs1 * 64 + qs0 * 16) = u.hv;
    }
    __syncthreads();
#pragma unroll
    for (int h = 0; h < 2; ++h) {
      const char* Ah = lds + h * 8192;
      const char* Bh = lds + 16384 + h * 8192;
      half8 af[4], bf[4];
#pragma unroll
      for (int m4 = 0; m4 < 4; ++m4) {
        int row = wm * 64 + m4 * 16 + lr;
        af[m4] = *(const half8*)(Ah + row * 64 + lg * 16);
      }
#pragma unroll
      for (int n4 = 0; n4 < 4; ++n4) {
        int row = wn * 64 + n4 * 16 + lr;
        bf[n4] = *(const half8*)(Bh + row * 64 + lg * 16);
      }
#pragma unroll
      for (int m4 = 0; m4 < 4; ++m4)
#pragma unroll
        for (int n4 = 0; n4 < 4; ++n4)
          acc[m4][n4] = mfma16(af[m4], bf[n4], acc[m4][n4]);
    }
    __syncthreads();
  }

  // C epilogue: route through LDS halves for coalesced half8 stores to h-planes
  f16* cl = (f16*)lds;
  int rr = tid >> 2, c4 = tid & 3;
#pragma unroll
  for (int hm = 0; hm < 2; ++hm) {
    __syncthreads();
    if (wm == hm) {
#pragma unroll
      for (int m4 = 0; m4 < 4; ++m4)
#pragma unroll
        for (int n4 = 0; n4 < 4; ++n4)
#pragma unroll
          for (int r = 0; r < 4; ++r)
            cl[(m4 * 16 + lg * 4 + r) * 128 + wn * 64 + n4 * 16 + lr] = (f16)acc[m4][n4][r];
    }
    __syncthreads();
#pragma unroll
    for (int cc = 0; cc < 4; ++cc) {
      int pn = (n0 >> 5) + cc;
      half8 v = *(const half8*)(cl + rr * 128 + cc * 32 + c4 * 8);
      *(half8*)(CH + ((size_t)pn * NTOT + m0 + hm * 64 + rr) * 32 + c4 * 8) = v;
    }
  }
}

// ---------------- proj GEMM (m97 structure, BK=32, gload_lds A planes) ----------------
__global__ __launch_bounds__(256) void k_gemm_proj(const f16* __restrict__ A, const f16* __restrict__ Bw,
                                                   float* __restrict__ Cf32,
                                                   const float* __restrict__ bias, int N) {
  __shared__ __align__(16) char lds[16384];
  int per = gridDim.x >> 3;
  int wrk = (blockIdx.x & 7) * per + (blockIdx.x >> 3);
  int nNT = N >> 7;
  int mt = wrk / nNT, nt = wrk - mt * nNT;
  int m0 = mt * 128, n0 = nt * 128;
  int tid = threadIdx.x, w = tid >> 6, l = tid & 63, lr = l & 15, lg = l >> 4;
  int wm = w >> 1, wn = w & 1;
  f32x4 acc[4][4] = {};
  const char* Bb = (const char*)Bw + (size_t)n0 * 512;
  int rowA0 = 32 * w + (l >> 2);
  int rowA1 = rowA0 + 16;
  int koff = (l & 3) * 16;
  char* ldsA0 = lds + (2 * w) * 1024;
  char* ldsA1 = lds + (2 * w + 1) * 1024;
  char* ldsB0 = lds + 8192 + (2 * w) * 1024;
  char* ldsB1 = lds + 8192 + (2 * w + 1) * 1024;

  for (int k0 = 0; k0 < 256; k0 += 32) {
    const char* Ab = (const char*)A + ((size_t)(k0 >> 5) * NTOT + m0) * 64;
    gload16(Ab + (size_t)rowA0 * 64 + koff, ldsA0);
    gload16(Ab + (size_t)rowA1 * 64 + koff, ldsA1);
    gload16(Bb + (size_t)rowA0 * 512 + k0 * 2 + koff, ldsB0);
    gload16(Bb + (size_t)rowA1 * 512 + k0 * 2 + koff, ldsB1);
    __syncthreads();
    half8 af[4], bf[4];
#pragma unroll
    for (int m4 = 0; m4 < 4; ++m4) {
      int row = wm * 64 + m4 * 16 + lr;
      af[m4] = *(const half8*)(lds + row * 64 + lg * 16);
    }
#pragma unroll
    for (int n4 = 0; n4 < 4; ++n4) {
      int row = wn * 64 + n4 * 16 + lr;
      bf[n4] = *(const half8*)(lds + 8192 + row * 64 + lg * 16);
    }
#pragma unroll
    for (int m4 = 0; m4 < 4; ++m4)
#pragma unroll
      for (int n4 = 0; n4 < 4; ++n4)
        acc[m4][n4] = mfma16(af[m4], bf[n4], acc[m4][n4]);
    __syncthreads();
  }

#pragma unroll
  for (int n4 = 0; n4 < 4; ++n4) {
    int n = n0 + wn * 64 + n4 * 16 + lr;
#pragma unroll
    for (int m4 = 0; m4 < 4; ++m4)
#pragma unroll
      for (int r = 0; r < 4; ++r) {
        int m = m0 + wm * 64 + m4 * 16 + lg * 4 + r;
        Cf32[(size_t)m * N + n] = acc[m4][n4][r] + bias[n];
      }
  }
}

// ---------------- agent pooling (scaled) + token means ----------------
__global__ __launch_bounds__(256) void k_pool_tw(const f16* qkvH, f16* agent, float* tw) {
  int bh = blockIdx.x, b = bh >> 3, h = bh & 7;
  int tid = threadIdx.x;
  const f16* qp0 = qkvH + ((size_t)h * NTOT + (size_t)b * NTOK) * 32;
  {
    int a = tid >> 2, c = tid & 3;
    float s8[8] = {};
    if (a < NA) {
      int dh = a / 7, dwi = a - dh * 7;
      for (int i = 0; i < 8; ++i)
#pragma unroll
        for (int j = 0; j < 8; ++j) {
          int tok = (dh * 8 + i) * 56 + dwi * 8 + j;
          half8 v = *(const half8*)(qp0 + (size_t)tok * 32 + c * 8);
#pragma unroll
          for (int e = 0; e < 8; ++e) s8[e] += (float)v[e];
        }
    }
    half8 o;
#pragma unroll
    for (int e = 0; e < 8; ++e) o[e] = (f16)(s8[e] * (SCALE / 64.f));
    *(half8*)(agent + (size_t)bh * NAP * 32 + a * 32 + c * 8) = o;
  }
  for (int n = tid; n < NTOK; n += 256) {
    const half8* qp = (const half8*)(qp0 + (size_t)n * 32);
    float sum = 0.f;
#pragma unroll
    for (int j = 0; j < 4; ++j) {
      half8 v = qp[j];
#pragma unroll
      for (int e = 0; e < 8; ++e) sum += (float)v[e];
    }
    tw[(size_t)bh * NTOK + n] = sum * (1.f / 32.f);
  }
}

// ---------------- two-phase exact top-k (desc value, asc index) ----------------
template <int NE, int J>
__device__ __forceinline__ void stage_local(unsigned long long (&key)[NE], int kmask, int base) {
#pragma unroll
  for (int e = 0; e < NE; ++e) {
    if ((e & J) == 0) {
      bool desc = (((base + e) & kmask) == 0);
      unsigned long long a = key[e], c = key[e | J];
      if ((a < c) == desc) { key[e] = c; key[e | J] = a; }
    }
  }
}

__global__ __launch_bounds__(256, 1) void k_sort1(const float* tw, unsigned long long* keys64) {
  __shared__ unsigned long long lk[2048 + 128];
  int bh = blockIdx.x >> 1, half = blockIdx.x & 1;
  int tid = threadIdx.x;
  const float* p = tw + (size_t)bh * NTOK;
  int gbase = half * 2048 + tid * 8;
  unsigned long long key[8];
#pragma unroll
  for (int e = 0; e < 8; ++e) {
    int s = gbase + e;
    float v = (s < NTOK) ? p[s] : -1e30f;
    unsigned ub = __float_as_uint(v);
    ub = (ub & 0x80000000u) ? ~ub : (ub | 0x80000000u);
    unsigned low = (s < NTOK) ? ~(unsigned)s : 0u;
    key[e] = ((unsigned long long)ub << 32) | low;
  }
  stage_local<8, 1>(key, 2, gbase);
  stage_local<8, 2>(key, 4, gbase); stage_local<8, 1>(key, 4, gbase);
  stage_local<8, 4>(key, 8, gbase); stage_local<8, 2>(key, 8, gbase); stage_local<8, 1>(key, 8, gbase);
  for (int k = 16; k <= 2048; k <<= 1) {
    bool desc = ((gbase & k) == 0);
    for (int j = k >> 1; j >= 8; j >>= 1) {
      int m = j >> 3;
      bool takeMax = (((tid & m) == 0) == desc);
      unsigned long long pv[8];
      if (m <= 32) {
#pragma unroll
        for (int e = 0; e < 8; ++e) pv[e] = __shfl_xor(key[e], m, 64);
      } else {
        __syncthreads();
#pragma unroll
        for (int e = 0; e < 8; ++e) { int ix = tid * 8 + e; lk[ix + (ix >> 4)] = key[e]; }
        __syncthreads();
        int pb = (tid ^ m) * 8;
#pragma unroll
        for (int e = 0; e < 8; ++e) { int ix = pb + e; pv[e] = lk[ix + (ix >> 4)]; }
      }
#pragma unroll
      for (int e = 0; e < 8; ++e)
        key[e] = takeMax ? (key[e] > pv[e] ? key[e] : pv[e])
                         : (key[e] < pv[e] ? key[e] : pv[e]);
    }
    stage_local<8, 4>(key, k, gbase);
    stage_local<8, 2>(key, k, gbase);
    stage_local<8, 1>(key, k, gbase);
  }
  unsigned long long* op = keys64 + (size_t)bh * 4096 + gbase;
#pragma unroll
  for (int e = 0; e < 8; ++e) op[e] = key[e];
}

__global__ __launch_bounds__(256, 1) void k_sort2(const unsigned long long* keys64, int* topidx) {
  __shared__ unsigned long long lk[4096 + 256];
  int bh = blockIdx.x, tid = threadIdx.x;
  const unsigned long long* ip = keys64 + (size_t)bh * 4096 + (size_t)tid * 16;
  unsigned long long key[16];
#pragma unroll
  for (int e = 0; e < 16; ++e) key[e] = ip[e];
  int base = tid * 16;
  for (int j = 2048; j >= 16; j >>= 1) {
    int m = j >> 4;
    bool takeMax = ((tid & m) == 0);
    unsigned long long pv[16];
    if (m <= 32) {
#pragma unroll
      for (int e = 0; e < 16; ++e) pv[e] = __shfl_xor(key[e], m, 64);
    } else {
      __syncthreads();
#pragma unroll
      for (int e = 0; e < 16; ++e) { int ix = base + e; lk[ix + (ix >> 4)] = key[e]; }
      __syncthreads();
      int pb = (tid ^ m) * 16;
#pragma unroll
      for (int e = 0; e < 16; ++e) { int ix = pb + e; pv[e] = lk[ix + (ix >> 4)]; }
    }
#pragma unroll
    for (int e = 0; e < 16; ++e)
      key[e] = takeMax ? (key[e] > pv[e] ? key[e] : pv[e])
                       : (key[e] < pv[e] ? key[e] : pv[e]);
  }
  stage_local<16, 8>(key, 4096, base);
  stage_local<16, 4>(key, 4096, base);
  stage_local<16, 2>(key, 4096, base);
  stage_local<16, 1>(key, 4096, base);
  if (tid < TTOP / 16) {
    int* op = topidx + (size_t)bh * TTOP + base;
#pragma unroll
    for (int e = 0; e < 16; ++e) op[e] = (int)(~(unsigned)key[e]);
  }
}

// ---------------- v transpose: vt[bh][d=32][n=3136] ----------------
__global__ __launch_bounds__(256) void k_vt(const f16* qkvH, f16* vt) {
  __shared__ __align__(16) f16 t[64][40];
  int bh = blockIdx.y, b = bh >> 3, h = bh & 7;
  int n0 = blockIdx.x * 64;
  int tid = threadIdx.x;
  const f16* vp = qkvH + ((size_t)(16 + h) * NTOT + (size_t)b * NTOK + n0) * 32;
  {
    int nl = tid >> 2, c = tid & 3;
    *(half8*)(&t[nl][c * 8]) = *(const half8*)(vp + (size_t)nl * 32 + c * 8);
  }
  __syncthreads();
  for (int s = tid; s < 64 * 32; s += 256) {
    int d = s >> 6, nl = s & 63;
    vt[((size_t)(bh * 32 + d)) * NTOK + n0 + nl] = t[nl][d];
  }
}

// ---------------- fused agent attention, split-n partials ----------------
__global__ __launch_bounds__(256) void k_flash(const f16* qkvH, const f16* agent, const f16* vt,
                                               const float* pos_bias, float* opart, float* rspart) {
  __shared__ __align__(16) f16 pbuf[4][64][40];
  __shared__ float ored[64][33];
  __shared__ float rssum[64];
  int part = blockIdx.x, bh = blockIdx.y, b = bh >> 3, h = bh & 7;
  int tid = threadIdx.x, w = tid >> 6, l = tid & 63, lr = l & 15, lg = l >> 4;
  half8 afrag[4];
#pragma unroll
  for (int mt = 0; mt < 4; ++mt)
    afrag[mt] = *(const half8*)(agent + ((size_t)bh * 64 + mt * 16 + lr) * 32 + lg * 8);
  f32x4 o[4][2] = {};
  float rs[4][4] = {};
  const f16* kbase = qkvH + ((size_t)(8 + h) * NTOT + (size_t)b * NTOK) * 32;
  const f16* vtb = vt + (size_t)bh * 32 * NTOK;
  const float* pbb = pos_bias + (size_t)h * NAP * NTOK;
  f32x4 zero = {};
  for (int n0 = (part * 4 + w) * 32; n0 < NTOK; n0 += 512) {
#pragma unroll
    for (int t2 = 0; t2 < 2; ++t2) {
      int nc = n0 + t2 * 16;
      half8 kf = *(const half8*)(kbase + (size_t)(nc + lr) * 32 + lg * 8);
#pragma unroll
      for (int mt = 0; mt < 4; ++mt) {
        f32x4 s = mfma16(afrag[mt], kf, zero);
#pragma unroll
        for (int r = 0; r < 4; ++r) {
          int a = mt * 16 + lg * 4 + r;
          float pv = __expf(s[r] + pbb[(size_t)a * NTOK + nc + lr]);
          rs[mt][r] += pv;
          pbuf[w][a][t2 * 16 + lr] = (f16)pv;
        }
      }
    }
    half8 pf[4];
#pragma unroll
    for (int mt = 0; mt < 4; ++mt)
      pf[mt] = *(const half8*)(&pbuf[w][mt * 16 + lr][lg * 8]);
#pragma unroll
    for (int dt = 0; dt < 2; ++dt) {
      half8 vf = *(const half8*)(vtb + (size_t)(dt * 16 + lr) * NTOK + n0 + lg * 8);
#pragma unroll
      for (int mt = 0; mt < 4; ++mt)
        o[mt][dt] = mfma16(pf[mt], vf, o[mt][dt]);
    }
  }
#pragma unroll
  for (int mt = 0; mt < 4; ++mt)
#pragma unroll
    for (int r = 0; r < 4; ++r) {
      float v = rs[mt][r];
      for (int off = 1; off < 16; off <<= 1) v += __shfl_xor(v, off, 64);
      rs[mt][r] = v;
    }
  for (int s = tid; s < 64 * 33; s += 256) ((float*)ored)[s] = 0.f;
  if (tid < 64) rssum[tid] = 0.f;
  __syncthreads();
  for (int ww = 0; ww < 4; ++ww) {
    if (w == ww) {
      if (lr == 0)
#pragma unroll
        for (int mt = 0; mt < 4; ++mt)
#pragma unroll
          for (int r = 0; r < 4; ++r) rssum[mt * 16 + lg * 4 + r] += rs[mt][r];
#pragma unroll
      for (int mt = 0; mt < 4; ++mt)
#pragma unroll
        for (int dt = 0; dt < 2; ++dt)
#pragma unroll
          for (int r = 0; r < 4; ++r)
            ored[mt * 16 + lg * 4 + r][dt * 16 + lr] += o[mt][dt][r];
    }
    __syncthreads();
  }
  int pp = bh * FPARTS + part;
  for (int s = tid; s < NA * 32; s += 256) {
    int a = s >> 5, d = s & 31;
    opart[((size_t)pp * 64 + a) * 32 + d] = ored[a][d];
  }
  if (tid < NA) rspart[(size_t)pp * 64 + tid] = rssum[tid];
}

// ---------------- k_fred: reduce flash partials -> agent_v ----------------
__global__ __launch_bounds__(256) void k_fred(const float* opart, const float* rspart, float* agv) {
  int bh = blockIdx.x, tid = threadIdx.x;
  for (int s = tid; s < NA * 32; s += 256) {
    int a = s >> 5, d = s & 31;
    float o = 0.f, rs = 0.f;
#pragma unroll
    for (int p = 0; p < FPARTS; ++p) {
      int pp = bh * FPARTS + p;
      o += opart[((size_t)pp * 64 + a) * 32 + d];
      rs += rspart[(size_t)pp * 64 + a];
    }
    agv[(size_t)bh * NA * 32 + s] = o / rs;
  }
}

// ---------------- k_po: fused q2-gather -> resize -> softmax -> P@avT + dwconv -> preH ----------------
__global__ __launch_bounds__(256) void k_po(const f16* __restrict__ qkvH, const f16* __restrict__ agent,
                                            const int* __restrict__ topidx,
                                            const f16* __restrict__ agbH,
                                            const float* __restrict__ agent_v,
                                            const float* __restrict__ dwc_w,
                                            const float* __restrict__ dwc_b,
                                            f16* __restrict__ preH) {
  __shared__ __align__(16) char uq[9728];         // q2buf[64][76] f16, later ctile[112][40] f16
  __shared__ __align__(16) f16 pbuf[7 * 8 * 16 * 8];
  __shared__ __align__(16) f16 avT[32][72];
  __shared__ __align__(16) f16 wconvh[9][32];
  __shared__ float bconv[32];
  f16 (*q2buf)[76] = (f16(*)[76])uq;
  f16 (*ctile)[40] = (f16(*)[40])uq;
  int wrk = (blockIdx.x & 7) * 448 + (blockIdx.x >> 3);
  int h = wrk / 448;
  int rem = wrk - h * 448;
  int b = rem / 28;
  int chunk = rem - b * 28;
  int bh = b * 8 + h;
  int tid = threadIdx.x, w = tid >> 6, l = tid & 63, lr = l & 15, lg = l >> 4;
  const f16* qplane = qkvH + ((size_t)h * NTOT + (size_t)b * NTOK) * 32;
  const f16* vp = qkvH + ((size_t)(16 + h) * NTOT + (size_t)b * NTOK) * 32;
  for (int s = tid; s < 32 * 64; s += 256) {
    int d = s >> 6, a = s & 63;
    avT[d][a] = (a < NA) ? (f16)agent_v[((size_t)bh * NA + a) * 32 + d] : (f16)0.f;
  }
  for (int s = tid; s < 32 * 9; s += 256) {
    int d = s / 9, t = s - d * 9;
    wconvh[t][d] = (f16)dwc_w[(size_t)(h * 32 + d) * 9 + t];
  }
  if (tid < 32) bconv[tid] = dwc_b[h * 32 + tid];
  half8 bfrag[4];
#pragma unroll
  for (int nt = 0; nt < 4; ++nt)
    bfrag[nt] = *(const half8*)(agent + ((size_t)bh * 64 + nt * 16 + lr) * 32 + lg * 8);
  int jbase = chunk * 56 - 4;
  f32x4 zero = {};
  {
    int j = jbase + w * 16 + lr;
    int jc = min(max(j, 0), TTOP - 1);
    int tok = topidx[(size_t)bh * TTOP + jc];
    half8 qf = *(const half8*)(qplane + (size_t)tok * 32 + lg * 8);
#pragma unroll
    for (int nt = 0; nt < 4; ++nt) {
      f32x4 s = mfma16(qf, bfrag[nt], zero);
#pragma unroll
      for (int r = 0; r < 4; ++r)
        q2buf[w * 16 + lg * 4 + r][nt * 16 + lr] = (f16)s[r];
    }
  }
  __syncthreads();
  if (tid < 224) {
    int ltok = tid >> 1, hc = tid & 1;
    int g = chunk * 112 + ltok;
    int hi = g >> 1;
    int jA, jB; float wAq, wBq;
    if (g & 1) { jA = hi; jB = hi + 1; wAq = 0.75f; wBq = 0.25f; }
    else       { jA = hi - 1; jB = hi; wAq = 0.25f; wBq = 0.75f; }
    jA = min(max(jA, 0), TTOP - 1);
    jB = min(max(jB, 0), TTOP - 1);
    int lA = jA - jbase, lB = jB - jbase;
    const f16* ab = agbH + ((size_t)(h * NTOK + g)) * NAP + hc * 32;
    half8 bias8[4];
#pragma unroll
    for (int cc = 0; cc < 4; ++cc) bias8[cc] = *(const half8*)(ab + cc * 8);
    f16 wAh = (f16)wAq, wBh = (f16)wBq;
    half8 wA8 = {wAh, wAh, wAh, wAh, wAh, wAh, wAh, wAh};
    half8 wB8 = {wBh, wBh, wBh, wBh, wBh, wBh, wBh, wBh};
    float ssum = 0.f;
    half8 oo[4];
#pragma unroll
    for (int cc = 0; cc < 4; ++cc) {
      int c = hc * 4 + cc;
      half8 a8 = *(const half8*)(&q2buf[lA][c * 8]);
      half8 b8 = *(const half8*)(&q2buf[lB][c * 8]);
      half8 v8 = a8 * wA8 + b8 * wB8 + bias8[cc];
#pragma unroll
      for (int e = 0; e < 8; ++e) {
        int a = c * 8 + e;
        float pv = 0.f;
        if (a < NA) {
          pv = __expf((float)v8[e]);
          ssum += pv;
        }
        oo[cc][e] = (f16)pv;
      }
    }
    ssum += __shfl_xor(ssum, 1, 64);
    f16 invs = (f16)(1.f / ssum);
    half8 iv8 = {invs, invs, invs, invs, invs, invs, invs, invs};
    int lt = ltok >> 4, lrr = ltok & 15;
#pragma unroll
    for (int cc = 0; cc < 4; ++cc) {
      int c = hc * 4 + cc;
      *(half8*)(pbuf + ((size_t)(lt * 8 + c) * 16 + lrr) * 8) = oo[cc] * iv8;
    }
  }
  __syncthreads();
  half8 bf[2][2];
#pragma unroll
  for (int nt = 0; nt < 2; ++nt)
#pragma unroll
    for (int ks = 0; ks < 2; ++ks)
      bf[nt][ks] = *(const half8*)(&avT[0][0] + (size_t)(nt * 16 + lr) * 72 + ks * 32 + lg * 8);
#pragma unroll
  for (int i = 0; i < 2; ++i) {
    int lt = w * 2 + i;
    if (lt >= 7) continue;
    half8 pa0 = *(const half8*)(pbuf + ((size_t)(lt * 8 + lg) * 16 + lr) * 8);
    half8 pa1 = *(const half8*)(pbuf + ((size_t)(lt * 8 + 4 + lg) * 16 + lr) * 8);
    f32x4 acc0 = {}, acc1 = {};
    acc0 = mfma16(pa0, bf[0][0], acc0);
    acc0 = mfma16(pa1, bf[0][1], acc0);
    acc1 = mfma16(pa0, bf[1][0], acc1);
    acc1 = mfma16(pa1, bf[1][1], acc1);
    int ltrow = lt * 16 + lg * 4;
#pragma unroll
    for (int r = 0; r < 4; ++r) {
      ctile[ltrow + r][lr] = (f16)acc0[r];
      ctile[ltrow + r][16 + lr] = (f16)acc1[r];
    }
  }
  if (tid >= 224) return;
  int ltok = tid >> 1, hc = tid & 1;
  int g = chunk * 112 + ltok;
  int ly = ltok / 56, x = ltok - ly * 56;
  int y = chunk * 2 + ly;
  half8 acch[2] = {};
#pragma unroll
  for (int ky = 0; ky < 3; ++ky) {
    int gy = y + ky - 1;
    if (gy < 0 || gy >= 56) continue;
#pragma unroll
    for (int kx = 0; kx < 3; ++kx) {
      int xx = x + kx - 1;
      if (xx < 0 || xx >= 56) continue;
      int t = ky * 3 + kx;
      const f16* vt9 = vp + (size_t)(gy * 56 + xx) * 32 + hc * 16;
#pragma unroll
      for (int c = 0; c < 2; ++c) {
        half8 wv = *(const half8*)(&wconvh[t][hc * 16 + c * 8]);
        half8 vv = *(const half8*)(vt9 + c * 8);
        acch[c] += wv * vv;
      }
    }
  }
  f16* op = preH + ((size_t)h * NTOT + (size_t)b * NTOK + g) * 32 + hc * 16;
#pragma unroll
  for (int c = 0; c < 2; ++c) {
    half8 cv = *(const half8*)(&ctile[ltok][hc * 16 + c * 8]);
    half8 o;
#pragma unroll
    for (int e = 0; e < 8; ++e)
      o[e] = (f16)((float)cv[e] + bconv[hc * 16 + c * 8 + e] + (float)acch[c][e]);
    *(half8*)(op + c * 8) = o;
  }
}

extern "C" void kernel_launch(void* const* d_in, const int* in_sizes, int n_in,
                              void* d_out, int out_size, void* d_ws, size_t ws_size,
                              hipStream_t stream) {
  const float* x     = (const float*)d_in[0];
  const float* Wq    = (const float*)d_in[3];
  const float* Wkv   = (const float*)d_in[4];
  const float* Wproj = (const float*)d_in[5];
  const float* bproj = (const float*)d_in[6];
  const float* dwc_w = (const float*)d_in[7];
  const float* dwc_b = (const float*)d_in[8];
  const float* an_b  = (const float*)d_in[9];
  const float* na_b  = (const float*)d_in[10];
  const float* ah_b  = (const float*)d_in[11];
  const float* aw_b  = (const float*)d_in[12];
  const float* ha_b  = (const float*)d_in[13];
  const float* wa_b  = (const float*)d_in[14];

  char* ws = (char*)d_ws;
  size_t off = 0;
  auto alloc = [&](size_t bytes) {
    void* p = ws + off;
    off = (off + bytes + 255) & ~(size_t)255;
    return p;
  };
  f16* wqkv    = (f16*)alloc((size_t)768 * 256 * 2);
  f16* wproj   = (f16*)alloc((size_t)256 * 256 * 2);
  f16* qkvH    = (f16*)alloc((size_t)24 * NTOT * 32 * 2);
  float* posb  = (float*)alloc((size_t)8 * NAP * NTOK * 4);
  f16* agbH    = (f16*)alloc((size_t)8 * NTOK * NAP * 2);
  f16* agent   = (f16*)alloc((size_t)128 * NAP * 32 * 2);
  float* tw    = (float*)alloc((size_t)128 * NTOK * 4);
  int* topidx  = (int*)alloc((size_t)128 * TTOP * 4);
  unsigned long long* keys64 = (unsigned long long*)alloc((size_t)128 * 4096 * 8);
  f16* vt      = (f16*)alloc((size_t)128 * 32 * NTOK * 2);
  float* agv   = (float*)alloc((size_t)128 * NA * 32 * 4);
  float* opart = (float*)alloc((size_t)128 * FPARTS * 64 * 32 * 4);
  float* rspart= (float*)alloc((size_t)128 * FPARTS * 64 * 4);
  f16* preH    = (f16*)alloc((size_t)8 * NTOT * 32 * 2);

  k_prep_w<<<1024, 256, 0, stream>>>(Wq, Wkv, Wproj, wqkv, wproj);
  k_bias<<<dim3(13, 8), 256, 0, stream>>>(an_b, na_b, ah_b, aw_b, ha_b, wa_b, posb, agbH);
  k_gemm_qkv<<<2352, 256, 0, stream>>>(x, wqkv, qkvH);
  k_pool_tw<<<128, 256, 0, stream>>>(qkvH, agent, tw);
  k_sort1<<<256, 256, 0, stream>>>(tw, keys64);
  k_sort2<<<128, 256, 0, stream>>>(keys64, topidx);
  k_vt<<<dim3(49, 128), 256, 0, stream>>>(qkvH, vt);
  k_flash<<<dim3(FPARTS, 128), 256, 0, stream>>>(qkvH, agent, vt, posb, opart, rspart);
  k_fred<<<128, 256, 0, stream>>>(opart, rspart, agv);
  k_po<<<3584, 256, 0, stream>>>(qkvH, agent, topidx, agbH, agv, dwc_w, dwc_b, preH);
  k_gemm_proj<<<784, 256, 0, stream>>>(preH, wproj, (float*)d_out, bproj, 256);
}

// Round 29
// 207.162 us; speedup vs baseline: 1.2256x; 1.0013x over previous
//
#include <hip/hip_runtime.h>
#include <stdint.h>

typedef _Float16 f16;
typedef _Float16 half8 __attribute__((ext_vector_type(8)));
typedef __fp16 fp16x2 __attribute__((ext_vector_type(2)));
typedef float f32x4 __attribute__((ext_vector_type(4)));

#define NBATCH 16
#define NTOK 3136
#define NTOT 50176          // NBATCH*NTOK
#define NH 8
#define NA 49
#define NAP 64
#define TTOP 1568
#define SCALE 0.17677669529663687f
#define FPARTS 4

__device__ __forceinline__ f32x4 mfma16(half8 a, half8 b, f32x4 c) {
  return __builtin_amdgcn_mfma_f32_16x16x32_f16(a, b, c, 0, 0, 0);
}

__device__ __forceinline__ void gload16(const void* g, void* l) {
  __builtin_amdgcn_global_load_lds(
      (const __attribute__((address_space(1))) void*)g,
      (__attribute__((address_space(3))) void*)l, 16, 0, 0);
}

// ---------------- weight conversion ----------------
__global__ __launch_bounds__(256) void k_prep_w(const float* Wq, const float* Wkv, const float* Wproj,
                                                f16* wqkv, f16* wproj) {
  int total1 = 768 * 256;
  int total = total1 + 256 * 256;
  for (int i = blockIdx.x * 256 + threadIdx.x; i < total; i += gridDim.x * 256) {
    if (i < total1) {
      int j = i >> 8, k = i & 255;
      float v = (j < 256) ? Wq[j * 256 + k] : Wkv[(j - 256) * 256 + k];
      wqkv[i] = (f16)v;
    } else {
      int i2 = i - total1;
      wproj[i2] = (f16)Wproj[i2];
    }
  }
}

// ---------------- bias precompute ----------------
__global__ __launch_bounds__(256) void k_bias(const float* an_b, const float* na_b,
                                              const float* ah_b, const float* aw_b,
                                              const float* ha_b, const float* wa_b,
                                              float* pos_bias, f16* agbH) {
  int n = blockIdx.x * 256 + threadIdx.x;
  int h = blockIdx.y;
  if (n >= NTOK) return;
  int y = n / 56, x = n - y * 56;
  float py = (y + 0.5f) * 0.125f - 0.5f;
  float px = (x + 0.5f) * 0.125f - 0.5f;
  int iy0 = (int)floorf(py); float fy = py - (float)iy0;
  int ix0 = (int)floorf(px); float fx = px - (float)ix0;
  int y0 = max(iy0, 0), y1 = min(iy0 + 1, 6);
  int x0 = max(ix0, 0), x1 = min(ix0 + 1, 6);
  float w00 = (1.f - fy) * (1.f - fx), w01 = (1.f - fy) * fx;
  float w10 = fy * (1.f - fx), w11 = fy * fx;
  f16* abp = agbH + ((size_t)(h * NTOK + n)) * NAP;
  for (int a = 0; a < NA; ++a) {
    const float* pa = an_b + (h * NA + a) * 49;
    float up_an = w00 * pa[y0 * 7 + x0] + w01 * pa[y0 * 7 + x1] +
                  w10 * pa[y1 * 7 + x0] + w11 * pa[y1 * 7 + x1];
    const float* pn = na_b + (h * NA + a) * 49;
    float up_na = w00 * pn[y0 * 7 + x0] + w01 * pn[y0 * 7 + x1] +
                  w10 * pn[y1 * 7 + x0] + w11 * pn[y1 * 7 + x1];
    float pb = up_an + ah_b[(h * NA + a) * 56 + y] + aw_b[(h * NA + a) * 56 + x];
    pos_bias[((size_t)(h * NAP + a)) * NTOK + n] = pb;
    float ab = up_na + ha_b[(h * 56 + y) * NA + a] + wa_b[(h * 56 + x) * NA + a];
    abp[a] = (f16)ab;
  }
  for (int a = NA; a < NAP; ++a) {
    pos_bias[((size_t)(h * NAP + a)) * NTOK + n] = 0.f;
    abp[a] = (f16)0.f;
  }
}

// ---------------- qkv GEMM: BK=64, A f32 reg-staged through LDS, A-prefetch pipelined ----------------
// LDS: A0 8KB | A1 8KB | B0 8KB | B1 8KB = 32KB. 4 K-iterations (unrolled), 32 MFMA per barrier pair.
// A(k+1) register loads issue between barrier1 and compute(k): latency hides under MFMA.
__global__ __launch_bounds__(256) void k_gemm_qkv(const float* __restrict__ Af32,
                                                  const f16* __restrict__ Bw,
                                                  f16* __restrict__ CH) {
  __shared__ __align__(16) char lds[32768];
  const int N = 768;
  int per = gridDim.x >> 3;
  int wrk = (blockIdx.x & 7) * per + (blockIdx.x >> 3);
  int nNT = N >> 7;
  int mt = wrk / nNT, nt = wrk - mt * nNT;
  int m0 = mt * 128, n0 = nt * 128;
  int tid = threadIdx.x, w = tid >> 6, l = tid & 63, lr = l & 15, lg = l >> 4;
  int wm = w >> 1, wn = w & 1;
  f32x4 acc[4][4] = {};
  const char* Bb = (const char*)Bw + (size_t)n0 * 512;
  int rs0 = tid >> 2, qs0 = tid & 3;
  int rs1 = rs0 + 64;
  int rowB0 = 32 * w + (l >> 2);
  int rowB1 = rowB0 + 16;
  int koffB = (l & 3) * 16;
  char* ldsB0a = lds + 16384 + (2 * w) * 1024;
  char* ldsB0b = lds + 16384 + (2 * w + 1) * 1024;
  char* ldsB1a = lds + 24576 + (2 * w) * 1024;
  char* ldsB1b = lds + 24576 + (2 * w + 1) * 1024;
  const float* sA0 = Af32 + (size_t)(m0 + rs0) * 256 + qs0 * 8;
  const float* sA1 = Af32 + (size_t)(m0 + rs1) * 256 + qs0 * 8;

  // preload A(k0=0) into named regs (rule #20: no runtime-indexed arrays)
  float4 r0 = *(const float4*)(sA0),      r1 = *(const float4*)(sA0 + 4);
  float4 r2 = *(const float4*)(sA1),      r3 = *(const float4*)(sA1 + 4);
  float4 r4 = *(const float4*)(sA0 + 32), r5 = *(const float4*)(sA0 + 36);
  float4 r6 = *(const float4*)(sA1 + 32), r7 = *(const float4*)(sA1 + 36);

#pragma unroll
  for (int k0 = 0; k0 < 256; k0 += 64) {
    // B DMA (4 x 1KB per wave)
    gload16(Bb + (size_t)rowB0 * 512 + k0 * 2 + koffB, ldsB0a);
    gload16(Bb + (size_t)rowB1 * 512 + k0 * 2 + koffB, ldsB0b);
    gload16(Bb + (size_t)rowB0 * 512 + k0 * 2 + 64 + koffB, ldsB1a);
    gload16(Bb + (size_t)rowB1 * 512 + k0 * 2 + 64 + koffB, ldsB1b);
    // cvt + ds_write A(k0) from prefetched regs
    {
      union { half8 hv; fp16x2 h2[4]; } u;
      u.h2[0] = __builtin_amdgcn_cvt_pkrtz(r0.x, r0.y);
      u.h2[1] = __builtin_amdgcn_cvt_pkrtz(r0.z, r0.w);
      u.h2[2] = __builtin_amdgcn_cvt_pkrtz(r1.x, r1.y);
      u.h2[3] = __builtin_amdgcn_cvt_pkrtz(r1.z, r1.w);
      *(half8*)(lds + rs0 * 64 + qs0 * 16) = u.hv;
      u.h2[0] = __builtin_amdgcn_cvt_pkrtz(r2.x, r2.y);
      u.h2[1] = __builtin_amdgcn_cvt_pkrtz(r2.z, r2.w);
      u.h2[2] = __builtin_amdgcn_cvt_pkrtz(r3.x, r3.y);
      u.h2[3] = __builtin_amdgcn_cvt_pkrtz(r3.z, r3.w);
      *(half8*)(lds + rs1 * 64 + qs0 * 16) = u.hv;
      u.h2[0] = __builtin_amdgcn_cvt_pkrtz(r4.x, r4.y);
      u.h2[1] = __builtin_amdgcn_cvt_pkrtz(r4.z, r4.w);
      u.h2[2] = __builtin_amdgcn_cvt_pkrtz(r5.x, r5.y);
      u.h2[3] = __builtin_amdgcn_cvt_pkrtz(r5.z, r5.w);
      *(half8*)(lds + 8192 + rs0 * 64 + qs0 * 16) = u.hv;
      u.h2[0] = __builtin_amdgcn_cvt_pkrtz(r6.x, r6.y);
      u.h2[1] = __builtin_amdgcn_cvt_pkrtz(r6.z, r6.w);
      u.h2[2] = __builtin_amdgcn_cvt_pkrtz(r7.x, r7.y);
      u.h2[3] = __builtin_amdgcn_cvt_pkrtz(r7.z, r7.w);
      *(half8*)(lds + 8192 + rs1 * 64 + qs0 * 16) = u.hv;
    }
    __syncthreads();   // drains B DMA + A ds_writes
    // prefetch A(k0+64): in flight during the 32 MFMAs below
    if (k0 < 192) {
      const float* p0 = sA0 + k0 + 64;
      const float* p1 = sA1 + k0 + 64;
      r0 = *(const float4*)p0;        r1 = *(const float4*)(p0 + 4);
      r2 = *(const float4*)p1;        r3 = *(const float4*)(p1 + 4);
      r4 = *(const float4*)(p0 + 32); r5 = *(const float4*)(p0 + 36);
      r6 = *(const float4*)(p1 + 32); r7 = *(const float4*)(p1 + 36);
    }
#pragma unroll
    for (int h = 0; h < 2; ++h) {
      const char* Ah = lds + h * 8192;
      const char* Bh = lds + 16384 + h * 8192;
      half8 af[4], bf[4];
#pragma unroll
      for (int m4 = 0; m4 < 4; ++m4) {
        int row = wm * 64 + m4 * 16 + lr;
        af[m4] = *(const half8*)(Ah + row * 64 + lg * 16);
      }
#pragma unroll
      for (int n4 = 0; n4 < 4; ++n4) {
        int row = wn * 64 + n4 * 16 + lr;
        bf[n4] = *(const half8*)(Bh + row * 64 + lg * 16);
      }
#pragma unroll
      for (int m4 = 0; m4 < 4; ++m4)
#pragma unroll
        for (int n4 = 0; n4 < 4; ++n4)
          acc[m4][n4] = mfma16(af[m4], bf[n4], acc[m4][n4]);
    }
    __syncthreads();
  }

  // C epilogue: route through LDS halves for coalesced half8 stores to h-planes
  f16* cl = (f16*)lds;
  int rr = tid >> 2, c4 = tid & 3;
#pragma unroll
  for (int hm = 0; hm < 2; ++hm) {
    __syncthreads();
    if (wm == hm) {
#pragma unroll
      for (int m4 = 0; m4 < 4; ++m4)
#pragma unroll
        for (int n4 = 0; n4 < 4; ++n4)
#pragma unroll
          for (int r = 0; r < 4; ++r)
            cl[(m4 * 16 + lg * 4 + r) * 128 + wn * 64 + n4 * 16 + lr] = (f16)acc[m4][n4][r];
    }
    __syncthreads();
#pragma unroll
    for (int cc = 0; cc < 4; ++cc) {
      int pn = (n0 >> 5) + cc;
      half8 v = *(const half8*)(cl + rr * 128 + cc * 32 + c4 * 8);
      *(half8*)(CH + ((size_t)pn * NTOT + m0 + hm * 64 + rr) * 32 + c4 * 8) = v;
    }
  }
}

// ---------------- proj GEMM (m97 structure, BK=32, gload_lds A planes) ----------------
__global__ __launch_bounds__(256) void k_gemm_proj(const f16* __restrict__ A, const f16* __restrict__ Bw,
                                                   float* __restrict__ Cf32,
                                                   const float* __restrict__ bias, int N) {
  __shared__ __align__(16) char lds[16384];
  int per = gridDim.x >> 3;
  int wrk = (blockIdx.x & 7) * per + (blockIdx.x >> 3);
  int nNT = N >> 7;
  int mt = wrk / nNT, nt = wrk - mt * nNT;
  int m0 = mt * 128, n0 = nt * 128;
  int tid = threadIdx.x, w = tid >> 6, l = tid & 63, lr = l & 15, lg = l >> 4;
  int wm = w >> 1, wn = w & 1;
  f32x4 acc[4][4] = {};
  const char* Bb = (const char*)Bw + (size_t)n0 * 512;
  int rowA0 = 32 * w + (l >> 2);
  int rowA1 = rowA0 + 16;
  int koff = (l & 3) * 16;
  char* ldsA0 = lds + (2 * w) * 1024;
  char* ldsA1 = lds + (2 * w + 1) * 1024;
  char* ldsB0 = lds + 8192 + (2 * w) * 1024;
  char* ldsB1 = lds + 8192 + (2 * w + 1) * 1024;

  for (int k0 = 0; k0 < 256; k0 += 32) {
    const char* Ab = (const char*)A + ((size_t)(k0 >> 5) * NTOT + m0) * 64;
    gload16(Ab + (size_t)rowA0 * 64 + koff, ldsA0);
    gload16(Ab + (size_t)rowA1 * 64 + koff, ldsA1);
    gload16(Bb + (size_t)rowA0 * 512 + k0 * 2 + koff, ldsB0);
    gload16(Bb + (size_t)rowA1 * 512 + k0 * 2 + koff, ldsB1);
    __syncthreads();
    half8 af[4], bf[4];
#pragma unroll
    for (int m4 = 0; m4 < 4; ++m4) {
      int row = wm * 64 + m4 * 16 + lr;
      af[m4] = *(const half8*)(lds + row * 64 + lg * 16);
    }
#pragma unroll
    for (int n4 = 0; n4 < 4; ++n4) {
      int row = wn * 64 + n4 * 16 + lr;
      bf[n4] = *(const half8*)(lds + 8192 + row * 64 + lg * 16);
    }
#pragma unroll
    for (int m4 = 0; m4 < 4; ++m4)
#pragma unroll
      for (int n4 = 0; n4 < 4; ++n4)
        acc[m4][n4] = mfma16(af[m4], bf[n4], acc[m4][n4]);
    __syncthreads();
  }

#pragma unroll
  for (int n4 = 0; n4 < 4; ++n4) {
    int n = n0 + wn * 64 + n4 * 16 + lr;
#pragma unroll
    for (int m4 = 0; m4 < 4; ++m4)
#pragma unroll
      for (int r = 0; r < 4; ++r) {
        int m = m0 + wm * 64 + m4 * 16 + lg * 4 + r;
        Cf32[(size_t)m * N + n] = acc[m4][n4][r] + bias[n];
      }
  }
}

// ---------------- agent pooling (scaled) + token means ----------------
__global__ __launch_bounds__(256) void k_pool_tw(const f16* qkvH, f16* agent, float* tw) {
  int bh = blockIdx.x, b = bh >> 3, h = bh & 7;
  int tid = threadIdx.x;
  const f16* qp0 = qkvH + ((size_t)h * NTOT + (size_t)b * NTOK) * 32;
  {
    int a = tid >> 2, c = tid & 3;
    float s8[8] = {};
    if (a < NA) {
      int dh = a / 7, dwi = a - dh * 7;
      for (int i = 0; i < 8; ++i)
#pragma unroll
        for (int j = 0; j < 8; ++j) {
          int tok = (dh * 8 + i) * 56 + dwi * 8 + j;
          half8 v = *(const half8*)(qp0 + (size_t)tok * 32 + c * 8);
#pragma unroll
          for (int e = 0; e < 8; ++e) s8[e] += (float)v[e];
        }
    }
    half8 o;
#pragma unroll
    for (int e = 0; e < 8; ++e) o[e] = (f16)(s8[e] * (SCALE / 64.f));
    *(half8*)(agent + (size_t)bh * NAP * 32 + a * 32 + c * 8) = o;
  }
  for (int n = tid; n < NTOK; n += 256) {
    const half8* qp = (const half8*)(qp0 + (size_t)n * 32);
    float sum = 0.f;
#pragma unroll
    for (int j = 0; j < 4; ++j) {
      half8 v = qp[j];
#pragma unroll
      for (int e = 0; e < 8; ++e) sum += (float)v[e];
    }
    tw[(size_t)bh * NTOK + n] = sum * (1.f / 32.f);
  }
}

// ---------------- two-phase exact top-k (desc value, asc index) ----------------
template <int NE, int J>
__device__ __forceinline__ void stage_local(unsigned long long (&key)[NE], int kmask, int base) {
#pragma unroll
  for (int e = 0; e < NE; ++e) {
    if ((e & J) == 0) {
      bool desc = (((base + e) & kmask) == 0);
      unsigned long long a = key[e], c = key[e | J];
      if ((a < c) == desc) { key[e] = c; key[e | J] = a; }
    }
  }
}

__global__ __launch_bounds__(256, 1) void k_sort1(const float* tw, unsigned long long* keys64) {
  __shared__ unsigned long long lk[2048 + 128];
  int bh = blockIdx.x >> 1, half = blockIdx.x & 1;
  int tid = threadIdx.x;
  const float* p = tw + (size_t)bh * NTOK;
  int gbase = half * 2048 + tid * 8;
  unsigned long long key[8];
#pragma unroll
  for (int e = 0; e < 8; ++e) {
    int s = gbase + e;
    float v = (s < NTOK) ? p[s] : -1e30f;
    unsigned ub = __float_as_uint(v);
    ub = (ub & 0x80000000u) ? ~ub : (ub | 0x80000000u);
    unsigned low = (s < NTOK) ? ~(unsigned)s : 0u;
    key[e] = ((unsigned long long)ub << 32) | low;
  }
  stage_local<8, 1>(key, 2, gbase);
  stage_local<8, 2>(key, 4, gbase); stage_local<8, 1>(key, 4, gbase);
  stage_local<8, 4>(key, 8, gbase); stage_local<8, 2>(key, 8, gbase); stage_local<8, 1>(key, 8, gbase);
  for (int k = 16; k <= 2048; k <<= 1) {
    bool desc = ((gbase & k) == 0);
    for (int j = k >> 1; j >= 8; j >>= 1) {
      int m = j >> 3;
      bool takeMax = (((tid & m) == 0) == desc);
      unsigned long long pv[8];
      if (m <= 32) {
#pragma unroll
        for (int e = 0; e < 8; ++e) pv[e] = __shfl_xor(key[e], m, 64);
      } else {
        __syncthreads();
#pragma unroll
        for (int e = 0; e < 8; ++e) { int ix = tid * 8 + e; lk[ix + (ix >> 4)] = key[e]; }
        __syncthreads();
        int pb = (tid ^ m) * 8;
#pragma unroll
        for (int e = 0; e < 8; ++e) { int ix = pb + e; pv[e] = lk[ix + (ix >> 4)]; }
      }
#pragma unroll
      for (int e = 0; e < 8; ++e)
        key[e] = takeMax ? (key[e] > pv[e] ? key[e] : pv[e])
                         : (key[e] < pv[e] ? key[e] : pv[e]);
    }
    stage_local<8, 4>(key, k, gbase);
    stage_local<8, 2>(key, k, gbase);
    stage_local<8, 1>(key, k, gbase);
  }
  unsigned long long* op = keys64 + (size_t)bh * 4096 + gbase;
#pragma unroll
  for (int e = 0; e < 8; ++e) op[e] = key[e];
}

__global__ __launch_bounds__(256, 1) void k_sort2(const unsigned long long* keys64, int* topidx) {
  __shared__ unsigned long long lk[4096 + 256];
  int bh = blockIdx.x, tid = threadIdx.x;
  const unsigned long long* ip = keys64 + (size_t)bh * 4096 + (size_t)tid * 16;
  unsigned long long key[16];
#pragma unroll
  for (int e = 0; e < 16; ++e) key[e] = ip[e];
  int base = tid * 16;
  for (int j = 2048; j >= 16; j >>= 1) {
    int m = j >> 4;
    bool takeMax = ((tid & m) == 0);
    unsigned long long pv[16];
    if (m <= 32) {
#pragma unroll
      for (int e = 0; e < 16; ++e) pv[e] = __shfl_xor(key[e], m, 64);
    } else {
      __syncthreads();
#pragma unroll
      for (int e = 0; e < 16; ++e) { int ix = base + e; lk[ix + (ix >> 4)] = key[e]; }
      __syncthreads();
      int pb = (tid ^ m) * 16;
#pragma unroll
      for (int e = 0; e < 16; ++e) { int ix = pb + e; pv[e] = lk[ix + (ix >> 4)]; }
    }
#pragma unroll
    for (int e = 0; e < 16; ++e)
      key[e] = takeMax ? (key[e] > pv[e] ? key[e] : pv[e])
                       : (key[e] < pv[e] ? key[e] : pv[e]);
  }
  stage_local<16, 8>(key, 4096, base);
  stage_local<16, 4>(key, 4096, base);
  stage_local<16, 2>(key, 4096, base);
  stage_local<16, 1>(key, 4096, base);
  if (tid < TTOP / 16) {
    int* op = topidx + (size_t)bh * TTOP + base;
#pragma unroll
    for (int e = 0; e < 16; ++e) op[e] = (int)(~(unsigned)key[e]);
  }
}

// ---------------- v transpose: vt[bh][d=32][n=3136] ----------------
__global__ __launch_bounds__(256) void k_vt(const f16* qkvH, f16* vt) {
  __shared__ __align__(16) f16 t[64][40];
  int bh = blockIdx.y, b = bh >> 3, h = bh & 7;
  int n0 = blockIdx.x * 64;
  int tid = threadIdx.x;
  const f16* vp = qkvH + ((size_t)(16 + h) * NTOT + (size_t)b * NTOK + n0) * 32;
  {
    int nl = tid >> 2, c = tid & 3;
    *(half8*)(&t[nl][c * 8]) = *(const half8*)(vp + (size_t)nl * 32 + c * 8);
  }
  __syncthreads();
  for (int s = tid; s < 64 * 32; s += 256) {
    int d = s >> 6, nl = s & 63;
    vt[((size_t)(bh * 32 + d)) * NTOK + n0 + nl] = t[nl][d];
  }
}

// ---------------- fused agent attention, split-n partials ----------------
__global__ __launch_bounds__(256) void k_flash(const f16* qkvH, const f16* agent, const f16* vt,
                                               const float* pos_bias, float* opart, float* rspart) {
  __shared__ __align__(16) f16 pbuf[4][64][40];
  __shared__ float ored[64][33];
  __shared__ float rssum[64];
  int part = blockIdx.x, bh = blockIdx.y, b = bh >> 3, h = bh & 7;
  int tid = threadIdx.x, w = tid >> 6, l = tid & 63, lr = l & 15, lg = l >> 4;
  half8 afrag[4];
#pragma unroll
  for (int mt = 0; mt < 4; ++mt)
    afrag[mt] = *(const half8*)(agent + ((size_t)bh * 64 + mt * 16 + lr) * 32 + lg * 8);
  f32x4 o[4][2] = {};
  float rs[4][4] = {};
  const f16* kbase = qkvH + ((size_t)(8 + h) * NTOT + (size_t)b * NTOK) * 32;
  const f16* vtb = vt + (size_t)bh * 32 * NTOK;
  const float* pbb = pos_bias + (size_t)h * NAP * NTOK;
  f32x4 zero = {};
  for (int n0 = (part * 4 + w) * 32; n0 < NTOK; n0 += 512) {
#pragma unroll
    for (int t2 = 0; t2 < 2; ++t2) {
      int nc = n0 + t2 * 16;
      half8 kf = *(const half8*)(kbase + (size_t)(nc + lr) * 32 + lg * 8);
#pragma unroll
      for (int mt = 0; mt < 4; ++mt) {
        f32x4 s = mfma16(afrag[mt], kf, zero);
#pragma unroll
        for (int r = 0; r < 4; ++r) {
          int a = mt * 16 + lg * 4 + r;
          float pv = __expf(s[r] + pbb[(size_t)a * NTOK + nc + lr]);
          rs[mt][r] += pv;
          pbuf[w][a][t2 * 16 + lr] = (f16)pv;
        }
      }
    }
    half8 pf[4];
#pragma unroll
    for (int mt = 0; mt < 4; ++mt)
      pf[mt] = *(const half8*)(&pbuf[w][mt * 16 + lr][lg * 8]);
#pragma unroll
    for (int dt = 0; dt < 2; ++dt) {
      half8 vf = *(const half8*)(vtb + (size_t)(dt * 16 + lr) * NTOK + n0 + lg * 8);
#pragma unroll
      for (int mt = 0; mt < 4; ++mt)
        o[mt][dt] = mfma16(pf[mt], vf, o[mt][dt]);
    }
  }
#pragma unroll
  for (int mt = 0; mt < 4; ++mt)
#pragma unroll
    for (int r = 0; r < 4; ++r) {
      float v = rs[mt][r];
      for (int off = 1; off < 16; off <<= 1) v += __shfl_xor(v, off, 64);
      rs[mt][r] = v;
    }
  for (int s = tid; s < 64 * 33; s += 256) ((float*)ored)[s] = 0.f;
  if (tid < 64) rssum[tid] = 0.f;
  __syncthreads();
  for (int ww = 0; ww < 4; ++ww) {
    if (w == ww) {
      if (lr == 0)
#pragma unroll
        for (int mt = 0; mt < 4; ++mt)
#pragma unroll
          for (int r = 0; r < 4; ++r) rssum[mt * 16 + lg * 4 + r] += rs[mt][r];
#pragma unroll
      for (int mt = 0; mt < 4; ++mt)
#pragma unroll
        for (int dt = 0; dt < 2; ++dt)
#pragma unroll
          for (int r = 0; r < 4; ++r)
            ored[mt * 16 + lg * 4 + r][dt * 16 + lr] += o[mt][dt][r];
    }
    __syncthreads();
  }
  int pp = bh * FPARTS + part;
  for (int s = tid; s < NA * 32; s += 256) {
    int a = s >> 5, d = s & 31;
    opart[((size_t)pp * 64 + a) * 32 + d] = ored[a][d];
  }
  if (tid < NA) rspart[(size_t)pp * 64 + tid] = rssum[tid];
}

// ---------------- k_fred: reduce flash partials -> agent_v ----------------
__global__ __launch_bounds__(256) void k_fred(const float* opart, const float* rspart, float* agv) {
  int bh = blockIdx.x, tid = threadIdx.x;
  for (int s = tid; s < NA * 32; s += 256) {
    int a = s >> 5, d = s & 31;
    float o = 0.f, rs = 0.f;
#pragma unroll
    for (int p = 0; p < FPARTS; ++p) {
      int pp = bh * FPARTS + p;
      o += opart[((size_t)pp * 64 + a) * 32 + d];
      rs += rspart[(size_t)pp * 64 + a];
    }
    agv[(size_t)bh * NA * 32 + s] = o / rs;
  }
}

// ---------------- k_po: fused q2-gather -> resize -> softmax -> P@avT + dwconv -> preH ----------------
__global__ __launch_bounds__(256) void k_po(const f16* __restrict__ qkvH, const f16* __restrict__ agent,
                                            const int* __restrict__ topidx,
                                            const f16* __restrict__ agbH,
                                            const float* __restrict__ agent_v,
                                            const float* __restrict__ dwc_w,
                                            const float* __restrict__ dwc_b,
                                            f16* __restrict__ preH) {
  __shared__ __align__(16) char uq[9728];         // q2buf[64][76] f16, later ctile[112][40] f16
  __shared__ __align__(16) f16 pbuf[7 * 8 * 16 * 8];
  __shared__ __align__(16) f16 avT[32][72];
  __shared__ __align__(16) f16 wconvh[9][32];
  __shared__ float bconv[32];
  f16 (*q2buf)[76] = (f16(*)[76])uq;
  f16 (*ctile)[40] = (f16(*)[40])uq;
  int wrk = (blockIdx.x & 7) * 448 + (blockIdx.x >> 3);
  int h = wrk / 448;
  int rem = wrk - h * 448;
  int b = rem / 28;
  int chunk = rem - b * 28;
  int bh = b * 8 + h;
  int tid = threadIdx.x, w = tid >> 6, l = tid & 63, lr = l & 15, lg = l >> 4;
  const f16* qplane = qkvH + ((size_t)h * NTOT + (size_t)b * NTOK) * 32;
  const f16* vp = qkvH + ((size_t)(16 + h) * NTOT + (size_t)b * NTOK) * 32;
  for (int s = tid; s < 32 * 64; s += 256) {
    int d = s >> 6, a = s & 63;
    avT[d][a] = (a < NA) ? (f16)agent_v[((size_t)bh * NA + a) * 32 + d] : (f16)0.f;
  }
  for (int s = tid; s < 32 * 9; s += 256) {
    int d = s / 9, t = s - d * 9;
    wconvh[t][d] = (f16)dwc_w[(size_t)(h * 32 + d) * 9 + t];
  }
  if (tid < 32) bconv[tid] = dwc_b[h * 32 + tid];
  half8 bfrag[4];
#pragma unroll
  for (int nt = 0; nt < 4; ++nt)
    bfrag[nt] = *(const half8*)(agent + ((size_t)bh * 64 + nt * 16 + lr) * 32 + lg * 8);
  int jbase = chunk * 56 - 4;
  f32x4 zero = {};
  {
    int j = jbase + w * 16 + lr;
    int jc = min(max(j, 0), TTOP - 1);
    int tok = topidx[(size_t)bh * TTOP + jc];
    half8 qf = *(const half8*)(qplane + (size_t)tok * 32 + lg * 8);
#pragma unroll
    for (int nt = 0; nt < 4; ++nt) {
      f32x4 s = mfma16(qf, bfrag[nt], zero);
#pragma unroll
      for (int r = 0; r < 4; ++r)
        q2buf[w * 16 + lg * 4 + r][nt * 16 + lr] = (f16)s[r];
    }
  }
  __syncthreads();
  if (tid < 224) {
    int ltok = tid >> 1, hc = tid & 1;
    int g = chunk * 112 + ltok;
    int hi = g >> 1;
    int jA, jB; float wAq, wBq;
    if (g & 1) { jA = hi; jB = hi + 1; wAq = 0.75f; wBq = 0.25f; }
    else       { jA = hi - 1; jB = hi; wAq = 0.25f; wBq = 0.75f; }
    jA = min(max(jA, 0), TTOP - 1);
    jB = min(max(jB, 0), TTOP - 1);
    int lA = jA - jbase, lB = jB - jbase;
    const f16* ab = agbH + ((size_t)(h * NTOK + g)) * NAP + hc * 32;
    half8 bias8[4];
#pragma unroll
    for (int cc = 0; cc < 4; ++cc) bias8[cc] = *(const half8*)(ab + cc * 8);
    f16 wAh = (f16)wAq, wBh = (f16)wBq;
    half8 wA8 = {wAh, wAh, wAh, wAh, wAh, wAh, wAh, wAh};
    half8 wB8 = {wBh, wBh, wBh, wBh, wBh, wBh, wBh, wBh};
    float ssum = 0.f;
    half8 oo[4];
#pragma unroll
    for (int cc = 0; cc < 4; ++cc) {
      int c = hc * 4 + cc;
      half8 a8 = *(const half8*)(&q2buf[lA][c * 8]);
      half8 b8 = *(const half8*)(&q2buf[lB][c * 8]);
      half8 v8 = a8 * wA8 + b8 * wB8 + bias8[cc];
#pragma unroll
      for (int e = 0; e < 8; ++e) {
        int a = c * 8 + e;
        float pv = 0.f;
        if (a < NA) {
          pv = __expf((float)v8[e]);
          ssum += pv;
        }
        oo[cc][e] = (f16)pv;
      }
    }
    ssum += __shfl_xor(ssum, 1, 64);
    f16 invs = (f16)(1.f / ssum);
    half8 iv8 = {invs, invs, invs, invs, invs, invs, invs, invs};
    int lt = ltok >> 4, lrr = ltok & 15;
#pragma unroll
    for (int cc = 0; cc < 4; ++cc) {
      int c = hc * 4 + cc;
      *(half8*)(pbuf + ((size_t)(lt * 8 + c) * 16 + lrr) * 8) = oo[cc] * iv8;
    }
  }
  __syncthreads();
  half8 bf[2][2];
#pragma unroll
  for (int nt = 0; nt < 2; ++nt)
#pragma unroll
    for (int ks = 0; ks < 2; ++ks)
      bf[nt][ks] = *(const half8*)(&avT[0][0] + (size_t)(nt * 16 + lr) * 72 + ks * 32 + lg * 8);
#pragma unroll
  for (int i = 0; i < 2; ++i) {
    int lt = w * 2 + i;
    if (lt >= 7) continue;
    half8 pa0 = *(const half8*)(pbuf + ((size_t)(lt * 8 + lg) * 16 + lr) * 8);
    half8 pa1 = *(const half8*)(pbuf + ((size_t)(lt * 8 + 4 + lg) * 16 + lr) * 8);
    f32x4 acc0 = {}, acc1 = {};
    acc0 = mfma16(pa0, bf[0][0], acc0);
    acc0 = mfma16(pa1, bf[0][1], acc0);
    acc1 = mfma16(pa0, bf[1][0], acc1);
    acc1 = mfma16(pa1, bf[1][1], acc1);
    int ltrow = lt * 16 + lg * 4;
#pragma unroll
    for (int r = 0; r < 4; ++r) {
      ctile[ltrow + r][lr] = (f16)acc0[r];
      ctile[ltrow + r][16 + lr] = (f16)acc1[r];
    }
  }
  if (tid >= 224) return;
  int ltok = tid >> 1, hc = tid & 1;
  int g = chunk * 112 + ltok;
  int ly = ltok / 56, x = ltok - ly * 56;
  int y = chunk * 2 + ly;
  half8 acch[2] = {};
#pragma unroll
  for (int ky = 0; ky < 3; ++ky) {
    int gy = y + ky - 1;
    if (gy < 0 || gy >= 56) continue;
#pragma unroll
    for (int kx = 0; kx < 3; ++kx) {
      int xx = x + kx - 1;
      if (xx < 0 || xx >= 56) continue;
      int t = ky * 3 + kx;
      const f16* vt9 = vp + (size_t)(gy * 56 + xx) * 32 + hc * 16;
#pragma unroll
      for (int c = 0; c < 2; ++c) {
        half8 wv = *(const half8*)(&wconvh[t][hc * 16 + c * 8]);
        half8 vv = *(const half8*)(vt9 + c * 8);
        acch[c] += wv * vv;
      }
    }
  }
  f16* op = preH + ((size_t)h * NTOT + (size_t)b * NTOK + g) * 32 + hc * 16;
#pragma unroll
  for (int c = 0; c < 2; ++c) {
    half8 cv = *(const half8*)(&ctile[ltok][hc * 16 + c * 8]);
    half8 o;
#pragma unroll
    for (int e = 0; e < 8; ++e)
      o[e] = (f16)((float)cv[e] + bconv[hc * 16 + c * 8 + e] + (float)acch[c][e]);
    *(half8*)(op + c * 8) = o;
  }
}

extern "C" void kernel_launch(void* const* d_in, const int* in_sizes, int n_in,
                              void* d_out, int out_size, void* d_ws, size_t ws_size,
                              hipStream_t stream) {
  const float* x     = (const float*)d_in[0];
  const float* Wq    = (const float*)d_in[3];
  const float* Wkv   = (const float*)d_in[4];
  const float* Wproj = (const float*)d_in[5];
  const float* bproj = (const float*)d_in[6];
  const float* dwc_w = (const float*)d_in[7];
  const float* dwc_b = (const float*)d_in[8];
  const float* an_b  = (const float*)d_in[9];
  const float* na_b  = (const float*)d_in[10];
  const float* ah_b  = (const float*)d_in[11];
  const float* aw_b  = (const float*)d_in[12];
  const float* ha_b  = (const float*)d_in[13];
  const float* wa_b  = (const float*)d_in[14];

  char* ws = (char*)d_ws;
  size_t off = 0;
  auto alloc = [&](size_t bytes) {
    void* p = ws + off;
    off = (off + bytes + 255) & ~(size_t)255;
    return p;
  };
  f16* wqkv    = (f16*)alloc((size_t)768 * 256 * 2);
  f16* wproj   = (f16*)alloc((size_t)256 * 256 * 2);
  f16* qkvH    = (f16*)alloc((size_t)24 * NTOT * 32 * 2);
  float* posb  = (float*)alloc((size_t)8 * NAP * NTOK * 4);
  f16* agbH    = (f16*)alloc((size_t)8 * NTOK * NAP * 2);
  f16* agent   = (f16*)alloc((size_t)128 * NAP * 32 * 2);
  float* tw    = (float*)alloc((size_t)128 * NTOK * 4);
  int* topidx  = (int*)alloc((size_t)128 * TTOP * 4);
  unsigned long long* keys64 = (unsigned long long*)alloc((size_t)128 * 4096 * 8);
  f16* vt      = (f16*)alloc((size_t)128 * 32 * NTOK * 2);
  float* agv   = (float*)alloc((size_t)128 * NA * 32 * 4);
  float* opart = (float*)alloc((size_t)128 * FPARTS * 64 * 32 * 4);
  float* rspart= (float*)alloc((size_t)128 * FPARTS * 64 * 4);
  f16* preH    = (f16*)alloc((size_t)8 * NTOT * 32 * 2);

  k_prep_w<<<1024, 256, 0, stream>>>(Wq, Wkv, Wproj, wqkv, wproj);
  k_bias<<<dim3(13, 8), 256, 0, stream>>>(an_b, na_b, ah_b, aw_b, ha_b, wa_b, posb, agbH);
  k_gemm_qkv<<<2352, 256, 0, stream>>>(x, wqkv, qkvH);
  k_pool_tw<<<128, 256, 0, stream>>>(qkvH, agent, tw);
  k_sort1<<<256, 256, 0, stream>>>(tw, keys64);
  k_sort2<<<128, 256, 0, stream>>>(keys64, topidx);
  k_vt<<<dim3(49, 128), 256, 0, stream>>>(qkvH, vt);
  k_flash<<<dim3(FPARTS, 128), 256, 0, stream>>>(qkvH, agent, vt, posb, opart, rspart);
  k_fred<<<128, 256, 0, stream>>>(opart, rspart, agv);
  k_po<<<3584, 256, 0, stream>>>(qkvH, agent, topidx, agbH, agv, dwc_w, dwc_b, preH);
  k_gemm_proj<<<784, 256, 0, stream>>>(preH, wproj, (float*)d_out, bproj, 256);
}